// Round 1
// baseline (781.852 us; speedup 1.0000x reference)
//
#include <hip/hip_runtime.h>

// Geo-FFNO forward: factored Fourier (DFT -> per-mode complex mix -> iDFT, 16 modes)
// + fused FFN (Linear 128->512, ReLU, Linear 512->128, +bias, LayerNorm).
// B=16, M=N=128, D=I=O=128, NM=16, H=512.
//
// Pipeline (all on `stream`):
//   k_setup  : trig tables Tc/Ts (fwd DFT) and IT (inverse, irfft semantics)
//   k_wpack  : packed complex-mix matrix [16][256][256]: [[Wre,Wim],[-Wim,Wre]]
//   k_fft    : per-slab truncated DFT -> F[row][k][re/im][i]  (fp32)
//   k_mix    : per-mode GEMM [2048x256]@[256x256]            (fp32)
//   k_icdft  : per-slab inverse [128x32]@[32x128] -> h       (fp32, h in d_out)
//   (x-branch repeats with w2, accumulates into h)
//   k_ffn    : bf16 MFMA fused FFN + LN, in-place on d_out
//
// ws usage: Tc(8K) Ts(8K) IT(16K) Wp(4M) buf0(33.5M) buf1(33.5M) ~= 71.2 MB

#define LN_EPS 1e-5f
#define NMODES 16
#define FROW 4096     // per-row F/f size: 16k * 2 * 128
#define HROW 16384    // per (b,m) h row: 128*128

typedef __attribute__((ext_vector_type(8))) short short8;
typedef __attribute__((ext_vector_type(4))) float f32x4;

__device__ __forceinline__ ushort f2bf(float f) {
    unsigned u = __float_as_uint(f);
    unsigned r = (u + 0x7FFFu + ((u >> 16) & 1u)) >> 16;   // RNE
    return (ushort)r;
}

// ---------------- tables ----------------
__global__ void k_setup(float* __restrict__ Tc, float* __restrict__ Ts,
                        float* __restrict__ IT) {
    const float invs = 0.08838834764831845f;  // 1/sqrt(128)
    for (int idx = threadIdx.x; idx < NMODES * 128; idx += blockDim.x) {
        int k = idx >> 7, n = idx & 127;
        int p = (k * n) & 127;                 // periodic reduction
        float th = (float)p * (6.283185307179586f / 128.0f);
        float c = cosf(th), s = sinf(th);
        Tc[idx] = c * invs;                    // forward: (1/sqrtN) cos
        Ts[idx] = -s * invs;                   // forward: -(1/sqrtN) sin
        float ck = (k == 0) ? invs : 2.0f * invs;
        IT[n * 32 + 2 * k]     = ck * c;       // inverse: c_k cos
        IT[n * 32 + 2 * k + 1] = -ck * s;      // inverse: -c_k sin
    }
}

// ---------------- packed complex-mix weights ----------------
// Wp[k][ip][op], ip = i (re) / 128+i (im), op = o (re out) / 128+o (im out)
__global__ void k_wpack(const float* __restrict__ w, float* __restrict__ Wp) {
    int idx = blockIdx.x * 256 + threadIdx.x;  // 16*256*256 = 1,048,576 exact
    int k  = idx >> 16;
    int ip = (idx >> 8) & 255;
    int op = idx & 255;
    int i = ip & 127, o = op & 127;
    const float* base = w + (((i << 7) | o) * NMODES + k) * 2;
    float re = base[0], im = base[1];
    float v = (ip < 128) ? ((op < 128) ? re : im)
                         : ((op < 128) ? -im : re);
    Wp[idx] = v;
}

// ---------------- truncated forward DFT ----------------
// mode 0 (y): block=(b,m)=row, reduce over n (stride 128)
// mode 1 (x): block=(b,n)=row, reduce over m (stride 16384)
__global__ __launch_bounds__(128) void k_fft(const float* __restrict__ x,
        const float* __restrict__ Tc, const float* __restrict__ Ts,
        float* __restrict__ F, int mode) {
    __shared__ float Tc_s[NMODES * 128];
    __shared__ float Ts_s[NMODES * 128];
    for (int e = threadIdx.x; e < NMODES * 128; e += 128) {
        Tc_s[e] = Tc[e];
        Ts_s[e] = Ts[e];
    }
    __syncthreads();
    int row = blockIdx.x;
    int base, ts;
    if (mode == 0) { base = row * HROW; ts = 128; }
    else { base = (row >> 7) * 2097152 + (row & 127) * 128; ts = 16384; }
    int i = threadIdx.x;
    float re[NMODES], im[NMODES];
#pragma unroll
    for (int k = 0; k < NMODES; ++k) { re[k] = 0.f; im[k] = 0.f; }
    for (int tb = 0; tb < 32; ++tb) {
        int t0 = tb * 4;
        float xv0 = x[base + (t0 + 0) * ts + i];
        float xv1 = x[base + (t0 + 1) * ts + i];
        float xv2 = x[base + (t0 + 2) * ts + i];
        float xv3 = x[base + (t0 + 3) * ts + i];
#pragma unroll
        for (int k = 0; k < NMODES; ++k) {
            f32x4 c4 = *(const f32x4*)&Tc_s[k * 128 + t0];
            f32x4 s4 = *(const f32x4*)&Ts_s[k * 128 + t0];
            re[k] += xv0 * c4[0] + xv1 * c4[1] + xv2 * c4[2] + xv3 * c4[3];
            im[k] += xv0 * s4[0] + xv1 * s4[1] + xv2 * s4[2] + xv3 * s4[3];
        }
    }
    float* outp = F + row * FROW;
#pragma unroll
    for (int k = 0; k < NMODES; ++k) {
        outp[k * 256 + i]       = re[k];
        outp[k * 256 + 128 + i] = im[k];
    }
}

// ---------------- per-mode channel mix GEMM ----------------
// out[row][kt*256+op] = sum_c A[row][kt*256+c] * Wp[kt][c][op]
__global__ __launch_bounds__(256) void k_mix(const float* __restrict__ A,
        const float* __restrict__ Wp, float* __restrict__ outF) {
    __shared__ float A_s[256 * 36];   // [c][r], pad 36 to break conflicts
    int kt = blockIdx.x & 15;
    int bm0 = (blockIdx.x >> 4) * 32;
    for (int e = threadIdx.x; e < 32 * 256; e += 256) {
        int r = e >> 8, c = e & 255;
        A_s[c * 36 + r] = A[(bm0 + r) * FROW + kt * 256 + c];
    }
    __syncthreads();
    int tc = threadIdx.x & 63, tr = threadIdx.x >> 6;   // tr wave-uniform
    float acc[8][4];
#pragma unroll
    for (int j = 0; j < 8; ++j)
#pragma unroll
        for (int q = 0; q < 4; ++q) acc[j][q] = 0.f;
    const float* wp = Wp + kt * 65536 + tc * 4;
    for (int kk = 0; kk < 256; ++kk) {
        f32x4 wv = *(const f32x4*)(wp + kk * 256);
        f32x4 a0 = *(const f32x4*)&A_s[kk * 36 + tr * 8];
        f32x4 a1 = *(const f32x4*)&A_s[kk * 36 + tr * 8 + 4];
#pragma unroll
        for (int q = 0; q < 4; ++q) {
            acc[0][q] += a0[0] * wv[q]; acc[1][q] += a0[1] * wv[q];
            acc[2][q] += a0[2] * wv[q]; acc[3][q] += a0[3] * wv[q];
            acc[4][q] += a1[0] * wv[q]; acc[5][q] += a1[1] * wv[q];
            acc[6][q] += a1[2] * wv[q]; acc[7][q] += a1[3] * wv[q];
        }
    }
#pragma unroll
    for (int j = 0; j < 8; ++j) {
        f32x4 v = { acc[j][0], acc[j][1], acc[j][2], acc[j][3] };
        *(f32x4*)&outF[(bm0 + tr * 8 + j) * FROW + kt * 256 + tc * 4] = v;
    }
}

// ---------------- inverse DFT ----------------
// mode 0: h[row*16384 + n*128 + o]  = sum_kp IT[n][kp] f[row][kp][o]   (write)
// mode 1: h[b*2097152 + m*16384 + n*128 + o] += ...                    (accumulate)
__global__ __launch_bounds__(256) void k_icdft(const float* __restrict__ f,
        const float* __restrict__ IT, float* __restrict__ h, int mode) {
    __shared__ float IT_s[128 * 32];
    __shared__ float f_s[32 * 128];
    int row = blockIdx.x;
    for (int e = threadIdx.x; e < 4096; e += 256) {
        IT_s[e] = IT[e];
        f_s[e]  = f[row * FROW + e];
    }
    __syncthreads();
    int o = threadIdx.x & 127, nh = threadIdx.x >> 7;
    int outbase, ostride;
    if (mode == 0) { outbase = row * HROW + o; ostride = 128; }
    else { outbase = (row >> 7) * 2097152 + (row & 127) * 128 + o; ostride = 16384; }
    for (int nb = 0; nb < 8; ++nb) {
        int n0 = nh * 64 + nb * 8;
        float acc[8];
#pragma unroll
        for (int j = 0; j < 8; ++j) acc[j] = 0.f;
#pragma unroll
        for (int kpb = 0; kpb < 8; ++kpb) {
            int kp0 = kpb * 4;
            float f0 = f_s[kp0 * 128 + o];
            float f1v = f_s[kp0 * 128 + 128 + o];
            float f2v = f_s[kp0 * 128 + 256 + o];
            float f3v = f_s[kp0 * 128 + 384 + o];
#pragma unroll
            for (int j = 0; j < 8; ++j) {
                f32x4 it = *(const f32x4*)&IT_s[(n0 + j) * 32 + kp0];
                acc[j] += f0 * it[0] + f1v * it[1] + f2v * it[2] + f3v * it[3];
            }
        }
        if (mode == 0) {
#pragma unroll
            for (int j = 0; j < 8; ++j) h[outbase + (n0 + j) * ostride] = acc[j];
        } else {
#pragma unroll
            for (int j = 0; j < 8; ++j) h[outbase + (n0 + j) * ostride] += acc[j];
        }
    }
}

// ---------------- fused FFN + LayerNorm (bf16 MFMA), in-place on h ----------------
// 32 rows/block, 4 waves, each wave owns a 32-col output slice.
__global__ __launch_bounds__(256) void k_ffn(float* __restrict__ hio,
        const float* __restrict__ w0, const float* __restrict__ b0,
        const float* __restrict__ w1, const float* __restrict__ b1,
        const float* __restrict__ g, const float* __restrict__ bb) {
    __shared__ __align__(16) char smem[53248];
    ushort* h_s  = (ushort*)smem;             // [32][136] bf16
    ushort* h1_s = (ushort*)(smem + 8704);    // [32][136] bf16
    ushort* w_s  = (ushort*)(smem + 17408);   // [128][136] bf16 (w0t, then w1t)
    float*  h2_s = (float*)(smem + 17408);    // [32][132] fp32 (aliases w_s, used after)
    float*  gb_s = (float*)(smem + 52224);    // [256]

    int tid = threadIdx.x;
    int R0 = blockIdx.x * 32;
    for (int e = tid; e < 4096; e += 256) {
        int r = e >> 7, d = e & 127;
        h_s[r * 136 + d] = f2bf(hio[(R0 + r) * 128 + d]);
    }
    if (tid < 128) { gb_s[tid] = g[tid]; gb_s[128 + tid] = bb[tid]; }
    __syncthreads();

    int lane = tid & 63, wid = tid >> 6;
    int wc = wid * 32;
    int frow = lane & 15;        // row (A) / col (B,D) within 16-tile
    int fk8 = (lane >> 4) * 8;   // k offset within 32-slice
    int fr4 = (lane >> 4) * 4;   // D-frag row offset

    // GEMM1 A-frags (h rows, K=128) are chunk-invariant: preload once.
    short8 a1f[2][4];
#pragma unroll
    for (int tr = 0; tr < 2; ++tr)
#pragma unroll
        for (int kk = 0; kk < 4; ++kk)
            a1f[tr][kk] = *(const short8*)&h_s[(tr * 16 + frow) * 136 + kk * 32 + fk8];

    f32x4 acc2[2][2];
#pragma unroll
    for (int a = 0; a < 2; ++a)
#pragma unroll
        for (int c = 0; c < 2; ++c) acc2[a][c] = {0.f, 0.f, 0.f, 0.f};

    for (int hc = 0; hc < 4; ++hc) {
        __syncthreads();   // prior GEMM2 done reading w_s
        // stage w0t: w_s[hl][k] = w0[k][hc*128+hl]
        for (int e = tid; e < 16384; e += 256) {
            int k = e >> 7, hl = e & 127;
            w_s[hl * 136 + k] = f2bf(w0[k * 512 + hc * 128 + hl]);
        }
        __syncthreads();
        // GEMM1: h1c = relu(h @ w0c + b0c)
        f32x4 acc1[2][2];
#pragma unroll
        for (int a = 0; a < 2; ++a)
#pragma unroll
            for (int c = 0; c < 2; ++c) acc1[a][c] = {0.f, 0.f, 0.f, 0.f};
#pragma unroll
        for (int kk = 0; kk < 4; ++kk) {
            short8 bfr[2];
#pragma unroll
            for (int tcb = 0; tcb < 2; ++tcb)
                bfr[tcb] = *(const short8*)&w_s[(wc + tcb * 16 + frow) * 136 + kk * 32 + fk8];
#pragma unroll
            for (int tr = 0; tr < 2; ++tr)
#pragma unroll
                for (int tcb = 0; tcb < 2; ++tcb)
                    acc1[tr][tcb] = __builtin_amdgcn_mfma_f32_16x16x32_bf16(
                        a1f[tr][kk], bfr[tcb], acc1[tr][tcb], 0, 0, 0);
        }
#pragma unroll
        for (int tcb = 0; tcb < 2; ++tcb) {
            int col = wc + tcb * 16 + frow;
            float b0v = b0[hc * 128 + col];
#pragma unroll
            for (int tr = 0; tr < 2; ++tr)
#pragma unroll
                for (int r = 0; r < 4; ++r) {
                    float v = acc1[tr][tcb][r] + b0v;
                    h1_s[(tr * 16 + fr4 + r) * 136 + col] = f2bf(fmaxf(v, 0.f));
                }
        }
        __syncthreads();
        // stage w1t: w_s[ol][hl] = w1[(hc*128+hl)][ol]
        for (int e = tid; e < 16384; e += 256) {
            int hl = e >> 7, ol = e & 127;
            w_s[ol * 136 + hl] = f2bf(w1[(hc * 128 + hl) * 128 + ol]);
        }
        __syncthreads();
        // GEMM2: h2 += h1c @ w1c
#pragma unroll
        for (int kk = 0; kk < 4; ++kk) {
            short8 a2f[2], b2f[2];
#pragma unroll
            for (int tr = 0; tr < 2; ++tr)
                a2f[tr] = *(const short8*)&h1_s[(tr * 16 + frow) * 136 + kk * 32 + fk8];
#pragma unroll
            for (int tcb = 0; tcb < 2; ++tcb)
                b2f[tcb] = *(const short8*)&w_s[(wc + tcb * 16 + frow) * 136 + kk * 32 + fk8];
#pragma unroll
            for (int tr = 0; tr < 2; ++tr)
#pragma unroll
                for (int tcb = 0; tcb < 2; ++tcb)
                    acc2[tr][tcb] = __builtin_amdgcn_mfma_f32_16x16x32_bf16(
                        a2f[tr], b2f[tcb], acc2[tr][tcb], 0, 0, 0);
        }
    }
    __syncthreads();   // done with w_s; reuse as h2_s
#pragma unroll
    for (int tcb = 0; tcb < 2; ++tcb) {
        int col = wc + tcb * 16 + frow;
        float b1v = b1[col];
#pragma unroll
        for (int tr = 0; tr < 2; ++tr)
#pragma unroll
            for (int r = 0; r < 4; ++r)
                h2_s[(tr * 16 + fr4 + r) * 132 + col] = acc2[tr][tcb][r] + b1v;
    }
    __syncthreads();
    // LayerNorm: 8 lanes per row, 16 elems each
    int rrow = tid >> 3, sub = tid & 7;
    const float* hr = &h2_s[rrow * 132 + sub * 16];
    float s = 0.f;
#pragma unroll
    for (int j = 0; j < 16; ++j) s += hr[j];
    s += __shfl_xor(s, 1); s += __shfl_xor(s, 2); s += __shfl_xor(s, 4);
    float mu = s * (1.0f / 128.0f);
    float s2 = 0.f;
#pragma unroll
    for (int j = 0; j < 16; ++j) { float dv = hr[j] - mu; s2 += dv * dv; }
    s2 += __shfl_xor(s2, 1); s2 += __shfl_xor(s2, 2); s2 += __shfl_xor(s2, 4);
    float rstd = rsqrtf(s2 * (1.0f / 128.0f) + LN_EPS);
    float* outp = &hio[(R0 + rrow) * 128 + sub * 16];
#pragma unroll
    for (int j = 0; j < 16; ++j) {
        int d = sub * 16 + j;
        outp[j] = (hr[j] - mu) * rstd * gb_s[d] + gb_s[128 + d];
    }
}

extern "C" void kernel_launch(void* const* d_in, const int* in_sizes, int n_in,
                              void* d_out, int out_size, void* d_ws, size_t ws_size,
                              hipStream_t stream) {
    (void)in_sizes; (void)n_in; (void)out_size; (void)ws_size;
    const float* x   = (const float*)d_in[0];
    const float* w1  = (const float*)d_in[1];
    const float* w2  = (const float*)d_in[2];
    const float* fw0 = (const float*)d_in[3];
    const float* fb0 = (const float*)d_in[4];
    const float* fw1 = (const float*)d_in[5];
    const float* fb1 = (const float*)d_in[6];
    const float* lng = (const float*)d_in[7];
    const float* lnb = (const float*)d_in[8];
    float* out = (float*)d_out;

    char* ws = (char*)d_ws;
    float* Tc   = (float*)(ws);
    float* Ts   = (float*)(ws + 8192);
    float* IT   = (float*)(ws + 16384);
    float* Wp   = (float*)(ws + 32768);
    float* buf0 = (float*)(ws + 32768 + 4194304);              // F  (33.5 MB)
    float* buf1 = (float*)(ws + 32768 + 4194304 + 33554432);   // f  (33.5 MB)

    k_setup<<<1, 256, 0, stream>>>(Tc, Ts, IT);

    // y-branch: DFT over n, mix with w1, inverse over n -> h (= d_out)
    k_wpack<<<4096, 256, 0, stream>>>(w1, Wp);
    k_fft  <<<2048, 128, 0, stream>>>(x, Tc, Ts, buf0, 0);
    k_mix  <<<1024, 256, 0, stream>>>(buf0, Wp, buf1);
    k_icdft<<<2048, 256, 0, stream>>>(buf1, IT, out, 0);

    // x-branch: DFT over m, mix with w2, inverse over m -> h +=
    k_wpack<<<4096, 256, 0, stream>>>(w2, Wp);
    k_fft  <<<2048, 128, 0, stream>>>(x, Tc, Ts, buf0, 1);
    k_mix  <<<1024, 256, 0, stream>>>(buf0, Wp, buf1);
    k_icdft<<<2048, 256, 0, stream>>>(buf1, IT, out, 1);

    // fused FFN + LayerNorm, in-place on d_out
    k_ffn<<<8192, 256, 0, stream>>>(out, fw0, fb0, fw1, fb1, lng, lnb);
}

// Round 2
// 585.226 us; speedup vs baseline: 1.3360x; 1.3360x over previous
//
#include <hip/hip_runtime.h>

// Geo-FFNO forward: factored Fourier (DFT -> per-mode complex mix -> iDFT, 16 modes)
// + fused FFN (Linear 128->512, ReLU, Linear 512->128, +bias, LayerNorm).
// B=16, M=N=128, D=I=O=128, NM=16, H=512.
//
// R1 change: k_ffn rebuilt — bf16 weights precomputed once (k_wcvt -> buf0),
// B-frags read straight from L2 (no LDS weight staging, no per-block f2bf),
// 64 rows/block, h1 chunked in LDS (35 KB -> 4 blocks/CU).

#define LN_EPS 1e-5f
#define NMODES 16
#define FROW 4096     // per-row F/f size: 16k * 2 * 128
#define HROW 16384    // per (b,m) h row: 128*128

typedef __attribute__((ext_vector_type(8))) short short8;
typedef __attribute__((ext_vector_type(4))) float f32x4;

__device__ __forceinline__ ushort f2bf(float f) {
    unsigned u = __float_as_uint(f);
    unsigned r = (u + 0x7FFFu + ((u >> 16) & 1u)) >> 16;   // RNE
    return (ushort)r;
}

// ---------------- tables ----------------
__global__ void k_setup(float* __restrict__ Tc, float* __restrict__ Ts,
                        float* __restrict__ IT) {
    const float invs = 0.08838834764831845f;  // 1/sqrt(128)
    for (int idx = threadIdx.x; idx < NMODES * 128; idx += blockDim.x) {
        int k = idx >> 7, n = idx & 127;
        int p = (k * n) & 127;                 // periodic reduction
        float th = (float)p * (6.283185307179586f / 128.0f);
        float c = cosf(th), s = sinf(th);
        Tc[idx] = c * invs;                    // forward: (1/sqrtN) cos
        Ts[idx] = -s * invs;                   // forward: -(1/sqrtN) sin
        float ck = (k == 0) ? invs : 2.0f * invs;
        IT[n * 32 + 2 * k]     = ck * c;       // inverse: c_k cos
        IT[n * 32 + 2 * k + 1] = -ck * s;      // inverse: -c_k sin
    }
}

// ---------------- packed complex-mix weights ----------------
__global__ void k_wpack(const float* __restrict__ w, float* __restrict__ Wp) {
    int idx = blockIdx.x * 256 + threadIdx.x;  // 16*256*256 = 1,048,576 exact
    int k  = idx >> 16;
    int ip = (idx >> 8) & 255;
    int op = idx & 255;
    int i = ip & 127, o = op & 127;
    const float* base = w + (((i << 7) | o) * NMODES + k) * 2;
    float re = base[0], im = base[1];
    float v = (ip < 128) ? ((op < 128) ? re : im)
                         : ((op < 128) ? -im : re);
    Wp[idx] = v;
}

// ---------------- bf16 FFN weights (once) ----------------
// w0t[h][k] = w0[k][h]  (512x128 bf16); w1t[o][h] = w1[h][o]  (128x512 bf16)
__global__ __launch_bounds__(256) void k_wcvt(const float* __restrict__ w0,
        const float* __restrict__ w1, ushort* __restrict__ w0t,
        ushort* __restrict__ w1t) {
    int idx = blockIdx.x * 256 + threadIdx.x;   // 65536
    int h = idx >> 7, k = idx & 127;
    w0t[idx] = f2bf(w0[k * 512 + h]);
    int o = idx >> 9, hh = idx & 511;
    w1t[idx] = f2bf(w1[hh * 128 + o]);
}

// ---------------- truncated forward DFT ----------------
__global__ __launch_bounds__(128) void k_fft(const float* __restrict__ x,
        const float* __restrict__ Tc, const float* __restrict__ Ts,
        float* __restrict__ F, int mode) {
    __shared__ float Tc_s[NMODES * 128];
    __shared__ float Ts_s[NMODES * 128];
    for (int e = threadIdx.x; e < NMODES * 128; e += 128) {
        Tc_s[e] = Tc[e];
        Ts_s[e] = Ts[e];
    }
    __syncthreads();
    int row = blockIdx.x;
    int base, ts;
    if (mode == 0) { base = row * HROW; ts = 128; }
    else { base = (row >> 7) * 2097152 + (row & 127) * 128; ts = 16384; }
    int i = threadIdx.x;
    float re[NMODES], im[NMODES];
#pragma unroll
    for (int k = 0; k < NMODES; ++k) { re[k] = 0.f; im[k] = 0.f; }
    for (int tb = 0; tb < 32; ++tb) {
        int t0 = tb * 4;
        float xv0 = x[base + (t0 + 0) * ts + i];
        float xv1 = x[base + (t0 + 1) * ts + i];
        float xv2 = x[base + (t0 + 2) * ts + i];
        float xv3 = x[base + (t0 + 3) * ts + i];
#pragma unroll
        for (int k = 0; k < NMODES; ++k) {
            f32x4 c4 = *(const f32x4*)&Tc_s[k * 128 + t0];
            f32x4 s4 = *(const f32x4*)&Ts_s[k * 128 + t0];
            re[k] += xv0 * c4[0] + xv1 * c4[1] + xv2 * c4[2] + xv3 * c4[3];
            im[k] += xv0 * s4[0] + xv1 * s4[1] + xv2 * s4[2] + xv3 * s4[3];
        }
    }
    float* outp = F + row * FROW;
#pragma unroll
    for (int k = 0; k < NMODES; ++k) {
        outp[k * 256 + i]       = re[k];
        outp[k * 256 + 128 + i] = im[k];
    }
}

// ---------------- per-mode channel mix GEMM ----------------
__global__ __launch_bounds__(256) void k_mix(const float* __restrict__ A,
        const float* __restrict__ Wp, float* __restrict__ outF) {
    __shared__ float A_s[256 * 36];   // [c][r], pad 36 to break conflicts
    int kt = blockIdx.x & 15;
    int bm0 = (blockIdx.x >> 4) * 32;
    for (int e = threadIdx.x; e < 32 * 256; e += 256) {
        int r = e >> 8, c = e & 255;
        A_s[c * 36 + r] = A[(bm0 + r) * FROW + kt * 256 + c];
    }
    __syncthreads();
    int tc = threadIdx.x & 63, tr = threadIdx.x >> 6;   // tr wave-uniform
    float acc[8][4];
#pragma unroll
    for (int j = 0; j < 8; ++j)
#pragma unroll
        for (int q = 0; q < 4; ++q) acc[j][q] = 0.f;
    const float* wp = Wp + kt * 65536 + tc * 4;
    for (int kk = 0; kk < 256; ++kk) {
        f32x4 wv = *(const f32x4*)(wp + kk * 256);
        f32x4 a0 = *(const f32x4*)&A_s[kk * 36 + tr * 8];
        f32x4 a1 = *(const f32x4*)&A_s[kk * 36 + tr * 8 + 4];
#pragma unroll
        for (int q = 0; q < 4; ++q) {
            acc[0][q] += a0[0] * wv[q]; acc[1][q] += a0[1] * wv[q];
            acc[2][q] += a0[2] * wv[q]; acc[3][q] += a0[3] * wv[q];
            acc[4][q] += a1[0] * wv[q]; acc[5][q] += a1[1] * wv[q];
            acc[6][q] += a1[2] * wv[q]; acc[7][q] += a1[3] * wv[q];
        }
    }
#pragma unroll
    for (int j = 0; j < 8; ++j) {
        f32x4 v = { acc[j][0], acc[j][1], acc[j][2], acc[j][3] };
        *(f32x4*)&outF[(bm0 + tr * 8 + j) * FROW + kt * 256 + tc * 4] = v;
    }
}

// ---------------- inverse DFT ----------------
__global__ __launch_bounds__(256) void k_icdft(const float* __restrict__ f,
        const float* __restrict__ IT, float* __restrict__ h, int mode) {
    __shared__ float IT_s[128 * 32];
    __shared__ float f_s[32 * 128];
    int row = blockIdx.x;
    for (int e = threadIdx.x; e < 4096; e += 256) {
        IT_s[e] = IT[e];
        f_s[e]  = f[row * FROW + e];
    }
    __syncthreads();
    int o = threadIdx.x & 127, nh = threadIdx.x >> 7;
    int outbase, ostride;
    if (mode == 0) { outbase = row * HROW + o; ostride = 128; }
    else { outbase = (row >> 7) * 2097152 + (row & 127) * 128 + o; ostride = 16384; }
    for (int nb = 0; nb < 8; ++nb) {
        int n0 = nh * 64 + nb * 8;
        float acc[8];
#pragma unroll
        for (int j = 0; j < 8; ++j) acc[j] = 0.f;
#pragma unroll
        for (int kpb = 0; kpb < 8; ++kpb) {
            int kp0 = kpb * 4;
            float f0 = f_s[kp0 * 128 + o];
            float f1v = f_s[kp0 * 128 + 128 + o];
            float f2v = f_s[kp0 * 128 + 256 + o];
            float f3v = f_s[kp0 * 128 + 384 + o];
#pragma unroll
            for (int j = 0; j < 8; ++j) {
                f32x4 it = *(const f32x4*)&IT_s[(n0 + j) * 32 + kp0];
                acc[j] += f0 * it[0] + f1v * it[1] + f2v * it[2] + f3v * it[3];
            }
        }
        if (mode == 0) {
#pragma unroll
            for (int j = 0; j < 8; ++j) h[outbase + (n0 + j) * ostride] = acc[j];
        } else {
#pragma unroll
            for (int j = 0; j < 8; ++j) h[outbase + (n0 + j) * ostride] += acc[j];
        }
    }
}

// ---------------- fused FFN + LayerNorm (bf16 MFMA), in-place on h ----------------
// 64 rows/block, 4 waves. Each wave: 64 rows x (GEMM1: 64 cols/chunk, GEMM2: 32 cols).
// Weights read as MFMA B-frags directly from global (L2-resident bf16).
__global__ __launch_bounds__(256) void k_ffn(float* __restrict__ hio,
        const ushort* __restrict__ w0t, const float* __restrict__ b0,
        const ushort* __restrict__ w1t, const float* __restrict__ b1,
        const float* __restrict__ g, const float* __restrict__ bb) {
    __shared__ __align__(16) char smem[33792 + 1024 + 512];
    ushort* h1_s = (ushort*)smem;            // [64][264] bf16 chunk (33792 B)
    float*  h2_s = (float*)smem;             // [64][132] f32 (aliases h1_s)
    float*  gb_s = (float*)(smem + 33792);   // [256]
    float*  mr_s = (float*)(smem + 34816);   // [64][2] mu, rstd

    int tid = threadIdx.x;
    int R0 = blockIdx.x * 64;
    if (tid < 128) { gb_s[tid] = g[tid]; gb_s[128 + tid] = bb[tid]; }

    int lane = tid & 63, wid = tid >> 6;
    int frow = lane & 15;        // row (A) / col (B,D) within 16-tile
    int fk8 = (lane >> 4) * 8;   // k offset within 32-slice
    int fr4 = (lane >> 4) * 4;   // D-frag row offset

    // Preload GEMM1 A-frags straight from global fp32 h, convert in-register.
    short8 a1f[4][4];
#pragma unroll
    for (int tr = 0; tr < 4; ++tr)
#pragma unroll
        for (int kk = 0; kk < 4; ++kk) {
            const float* src = &hio[(R0 + tr * 16 + frow) * 128 + kk * 32 + fk8];
            f32x4 v0 = *(const f32x4*)src;
            f32x4 v1 = *(const f32x4*)(src + 4);
            short8 t;
#pragma unroll
            for (int j = 0; j < 4; ++j) {
                t[j]     = (short)f2bf(v0[j]);
                t[4 + j] = (short)f2bf(v1[j]);
            }
            a1f[tr][kk] = t;
        }

    f32x4 acc2[4][2];
#pragma unroll
    for (int a = 0; a < 4; ++a)
#pragma unroll
        for (int c = 0; c < 2; ++c) acc2[a][c] = {0.f, 0.f, 0.f, 0.f};

    for (int hc = 0; hc < 2; ++hc) {
        __syncthreads();   // h1_s free for this chunk
        // GEMM1 chunk: h1[:, hc*256 + wid*64 + tc*16 + *]
#pragma unroll
        for (int tc = 0; tc < 4; ++tc) {
            int hcol = hc * 256 + wid * 64 + tc * 16 + frow;
            short8 bfr[4];
#pragma unroll
            for (int kk = 0; kk < 4; ++kk)
                bfr[kk] = *(const short8*)&w0t[hcol * 128 + kk * 32 + fk8];
            f32x4 acc1[4];
#pragma unroll
            for (int a = 0; a < 4; ++a) acc1[a] = {0.f, 0.f, 0.f, 0.f};
#pragma unroll
            for (int kk = 0; kk < 4; ++kk)
#pragma unroll
                for (int tr = 0; tr < 4; ++tr)
                    acc1[tr] = __builtin_amdgcn_mfma_f32_16x16x32_bf16(
                        a1f[tr][kk], bfr[kk], acc1[tr], 0, 0, 0);
            float b0v = b0[hcol];
            int lcol = wid * 64 + tc * 16 + frow;
#pragma unroll
            for (int tr = 0; tr < 4; ++tr)
#pragma unroll
                for (int r = 0; r < 4; ++r) {
                    float v = acc1[tr][r] + b0v;
                    h1_s[(tr * 16 + fr4 + r) * 264 + lcol] = f2bf(fmaxf(v, 0.f));
                }
        }
        __syncthreads();
        // GEMM2 partial over this chunk's K=256
#pragma unroll
        for (int kk = 0; kk < 8; ++kk) {
            short8 a2[4];
#pragma unroll
            for (int tr = 0; tr < 4; ++tr)
                a2[tr] = *(const short8*)&h1_s[(tr * 16 + frow) * 264 + kk * 32 + fk8];
#pragma unroll
            for (int tc = 0; tc < 2; ++tc) {
                int ocol = wid * 32 + tc * 16 + frow;
                short8 b2 = *(const short8*)&w1t[ocol * 512 + hc * 256 + kk * 32 + fk8];
#pragma unroll
                for (int tr = 0; tr < 4; ++tr)
                    acc2[tr][tc] = __builtin_amdgcn_mfma_f32_16x16x32_bf16(
                        a2[tr], b2, acc2[tr][tc], 0, 0, 0);
            }
        }
    }
    __syncthreads();   // h1_s done; reuse as h2_s
#pragma unroll
    for (int tc = 0; tc < 2; ++tc) {
        int ocol = wid * 32 + tc * 16 + frow;
        float b1v = b1[ocol];
#pragma unroll
        for (int tr = 0; tr < 4; ++tr)
#pragma unroll
            for (int r = 0; r < 4; ++r)
                h2_s[(tr * 16 + fr4 + r) * 132 + ocol] = acc2[tr][tc][r] + b1v;
    }
    __syncthreads();
    // LayerNorm stats: 4 lanes per row, 32 elems each
    int row = tid >> 2, sub = tid & 3;
    const float* hr = &h2_s[row * 132 + sub * 32];
    float s = 0.f;
#pragma unroll
    for (int j = 0; j < 32; ++j) s += hr[j];
    s += __shfl_xor(s, 1); s += __shfl_xor(s, 2);
    float mu = s * (1.0f / 128.0f);
    float s2 = 0.f;
#pragma unroll
    for (int j = 0; j < 32; ++j) { float dv = hr[j] - mu; s2 += dv * dv; }
    s2 += __shfl_xor(s2, 1); s2 += __shfl_xor(s2, 2);
    float rstd = rsqrtf(s2 * (1.0f / 128.0f) + LN_EPS);
    if (sub == 0) { mr_s[row * 2] = mu; mr_s[row * 2 + 1] = rstd; }
    __syncthreads();
    // coalesced affine output
    for (int e = tid; e < 2048; e += 256) {
        int r = e >> 5, d4 = (e & 31) * 4;
        float mu2 = mr_s[r * 2], rs = mr_s[r * 2 + 1];
        f32x4 v = *(const f32x4*)&h2_s[r * 132 + d4];
        f32x4 o;
#pragma unroll
        for (int j = 0; j < 4; ++j)
            o[j] = (v[j] - mu2) * rs * gb_s[d4 + j] + gb_s[128 + d4 + j];
        *(f32x4*)&hio[(R0 + r) * 128 + d4] = o;
    }
}

extern "C" void kernel_launch(void* const* d_in, const int* in_sizes, int n_in,
                              void* d_out, int out_size, void* d_ws, size_t ws_size,
                              hipStream_t stream) {
    (void)in_sizes; (void)n_in; (void)out_size; (void)ws_size;
    const float* x   = (const float*)d_in[0];
    const float* w1  = (const float*)d_in[1];
    const float* w2  = (const float*)d_in[2];
    const float* fw0 = (const float*)d_in[3];
    const float* fb0 = (const float*)d_in[4];
    const float* fw1 = (const float*)d_in[5];
    const float* fb1 = (const float*)d_in[6];
    const float* lng = (const float*)d_in[7];
    const float* lnb = (const float*)d_in[8];
    float* out = (float*)d_out;

    char* ws = (char*)d_ws;
    float* Tc   = (float*)(ws);
    float* Ts   = (float*)(ws + 8192);
    float* IT   = (float*)(ws + 16384);
    float* Wp   = (float*)(ws + 32768);
    float* buf0 = (float*)(ws + 32768 + 4194304);              // F  (33.5 MB)
    float* buf1 = (float*)(ws + 32768 + 4194304 + 33554432);   // f  (33.5 MB)

    k_setup<<<1, 256, 0, stream>>>(Tc, Ts, IT);

    // y-branch: DFT over n, mix with w1, inverse over n -> h (= d_out)
    k_wpack<<<4096, 256, 0, stream>>>(w1, Wp);
    k_fft  <<<2048, 128, 0, stream>>>(x, Tc, Ts, buf0, 0);
    k_mix  <<<1024, 256, 0, stream>>>(buf0, Wp, buf1);
    k_icdft<<<2048, 256, 0, stream>>>(buf1, IT, out, 0);

    // x-branch: DFT over m, mix with w2, inverse over m -> h +=
    k_wpack<<<4096, 256, 0, stream>>>(w2, Wp);
    k_fft  <<<2048, 128, 0, stream>>>(x, Tc, Ts, buf0, 1);
    k_mix  <<<1024, 256, 0, stream>>>(buf0, Wp, buf1);

    // bf16 FFN weights into buf0 (free after second k_mix): w0t 128KB + w1t 128KB
    ushort* w0t = (ushort*)buf0;
    ushort* w1t = (ushort*)(buf0 + 65536);
    k_wcvt <<<256, 256, 0, stream>>>(fw0, fw1, w0t, w1t);

    k_icdft<<<2048, 256, 0, stream>>>(buf1, IT, out, 1);

    // fused FFN + LayerNorm, in-place on d_out
    k_ffn<<<4096, 256, 0, stream>>>(out, w0t, fb0, w1t, fb1, lng, lnb);
}

// Round 3
// 563.960 us; speedup vs baseline: 1.3864x; 1.0377x over previous
//
#include <hip/hip_runtime.h>

// Geo-FFNO forward: factored Fourier (DFT -> per-mode complex mix -> iDFT, 16 modes)
// + fused FFN (Linear 128->512, ReLU, Linear 512->128, +bias, LayerNorm).
// B=16, M=N=128, D=I=O=128, NM=16, H=512.
//
// R2: (a) k_mix -> bf16x3 MFMA (hi/lo split, ~fp32 precision), W pre-split+transposed.
//     (b) k_ffn: 128-col chunks, biases/LN params in LDS, hierarchical LN epilogue
//         (no f32 h2 round-trip), LDS 23.5 KB for higher occupancy.

#define LN_EPS 1e-5f
#define NMODES 16
#define FROW 4096     // per-row F/f size: 16k * 2 * 128
#define HROW 16384    // per (b,m) h row: 128*128

typedef __attribute__((ext_vector_type(8))) short short8;
typedef __attribute__((ext_vector_type(4))) short short4v;
typedef __attribute__((ext_vector_type(4))) float f32x4;

__device__ __forceinline__ ushort f2bf(float f) {
    unsigned u = __float_as_uint(f);
    unsigned r = (u + 0x7FFFu + ((u >> 16) & 1u)) >> 16;   // RNE
    return (ushort)r;
}
__device__ __forceinline__ float bf2f(ushort h) {
    return __uint_as_float(((unsigned)h) << 16);
}

// ---------------- tables ----------------
__global__ void k_setup(float* __restrict__ Tc, float* __restrict__ Ts,
                        float* __restrict__ IT) {
    const float invs = 0.08838834764831845f;  // 1/sqrt(128)
    for (int idx = threadIdx.x; idx < NMODES * 128; idx += blockDim.x) {
        int k = idx >> 7, n = idx & 127;
        int p = (k * n) & 127;                 // periodic reduction
        float th = (float)p * (6.283185307179586f / 128.0f);
        float c = cosf(th), s = sinf(th);
        Tc[idx] = c * invs;                    // forward: (1/sqrtN) cos
        Ts[idx] = -s * invs;                   // forward: -(1/sqrtN) sin
        float ck = (k == 0) ? invs : 2.0f * invs;
        IT[n * 32 + 2 * k]     = ck * c;       // inverse: c_k cos
        IT[n * 32 + 2 * k + 1] = -ck * s;      // inverse: -c_k sin
    }
}

// ---------------- packed complex-mix weights, transposed, bf16 hi/lo ----------------
// Layout: [k][op][ip]  (so MFMA B-frags read 8 contiguous ip per op-row).
// value(ip,op): ip<128: (op<128? re : im); ip>=128: (op<128? -im : re)
__global__ void k_wpack(const float* __restrict__ w, ushort* __restrict__ Wph,
                        ushort* __restrict__ Wpl) {
    int idx = blockIdx.x * 256 + threadIdx.x;  // 16*256*256 = 1,048,576
    int k  = idx >> 16;
    int op = (idx >> 8) & 255;
    int ip = idx & 255;
    int i = ip & 127, o = op & 127;
    const float* base = w + (((i << 7) | o) * NMODES + k) * 2;
    float re = base[0], im = base[1];
    float v = (ip < 128) ? ((op < 128) ? re : im)
                         : ((op < 128) ? -im : re);
    ushort hi = f2bf(v);
    ushort lo = f2bf(v - bf2f(hi));
    Wph[idx] = hi;
    Wpl[idx] = lo;
}

// ---------------- bf16 FFN weights (once) ----------------
// w0t[h][k] = w0[k][h]  (512x128 bf16); w1t[o][h] = w1[h][o]  (128x512 bf16)
__global__ __launch_bounds__(256) void k_wcvt(const float* __restrict__ w0,
        const float* __restrict__ w1, ushort* __restrict__ w0t,
        ushort* __restrict__ w1t) {
    int idx = blockIdx.x * 256 + threadIdx.x;   // 65536
    int h = idx >> 7, k = idx & 127;
    w0t[idx] = f2bf(w0[k * 512 + h]);
    int o = idx >> 9, hh = idx & 511;
    w1t[idx] = f2bf(w1[hh * 128 + o]);
}

// ---------------- truncated forward DFT ----------------
__global__ __launch_bounds__(128) void k_fft(const float* __restrict__ x,
        const float* __restrict__ Tc, const float* __restrict__ Ts,
        float* __restrict__ F, int mode) {
    __shared__ float Tc_s[NMODES * 128];
    __shared__ float Ts_s[NMODES * 128];
    for (int e = threadIdx.x; e < NMODES * 128; e += 128) {
        Tc_s[e] = Tc[e];
        Ts_s[e] = Ts[e];
    }
    __syncthreads();
    int row = blockIdx.x;
    int base, ts;
    if (mode == 0) { base = row * HROW; ts = 128; }
    else { base = (row >> 7) * 2097152 + (row & 127) * 128; ts = 16384; }
    int i = threadIdx.x;
    float re[NMODES], im[NMODES];
#pragma unroll
    for (int k = 0; k < NMODES; ++k) { re[k] = 0.f; im[k] = 0.f; }
    for (int tb = 0; tb < 32; ++tb) {
        int t0 = tb * 4;
        float xv0 = x[base + (t0 + 0) * ts + i];
        float xv1 = x[base + (t0 + 1) * ts + i];
        float xv2 = x[base + (t0 + 2) * ts + i];
        float xv3 = x[base + (t0 + 3) * ts + i];
#pragma unroll
        for (int k = 0; k < NMODES; ++k) {
            f32x4 c4 = *(const f32x4*)&Tc_s[k * 128 + t0];
            f32x4 s4 = *(const f32x4*)&Ts_s[k * 128 + t0];
            re[k] += xv0 * c4[0] + xv1 * c4[1] + xv2 * c4[2] + xv3 * c4[3];
            im[k] += xv0 * s4[0] + xv1 * s4[1] + xv2 * s4[2] + xv3 * s4[3];
        }
    }
    float* outp = F + row * FROW;
#pragma unroll
    for (int k = 0; k < NMODES; ++k) {
        outp[k * 256 + i]       = re[k];
        outp[k * 256 + 128 + i] = im[k];
    }
}

// ---------------- per-mode channel mix, bf16x3 MFMA ----------------
// block: (kt, 32-row tile); 4 waves x (32 rows x 64 cols).
// out[r][op] = sum_ip A[r][ip] * W[ip][op], via (Ah+Al)(Wh+Wl) ~ AhWh+AhWl+AlWh.
__global__ __launch_bounds__(256) void k_mixm(const float* __restrict__ A,
        const ushort* __restrict__ Wph, const ushort* __restrict__ Wpl,
        float* __restrict__ outF) {
    __shared__ ushort Ah[32 * 264];
    __shared__ ushort Al[32 * 264];
    int tid = threadIdx.x;
    int kt = blockIdx.x & 15;
    int bm0 = (blockIdx.x >> 4) * 32;
    // stage A rows as hi/lo bf16
    {
        int row = tid >> 3, cg = tid & 7;
        const float* arow = A + (bm0 + row) * FROW + kt * 256 + cg * 32;
        ushort* ah = &Ah[row * 264 + cg * 32];
        ushort* al = &Al[row * 264 + cg * 32];
#pragma unroll
        for (int j = 0; j < 8; ++j) {
            f32x4 v = *(const f32x4*)(arow + j * 4);
            short4v h4, l4;
#pragma unroll
            for (int q = 0; q < 4; ++q) {
                ushort h = f2bf(v[q]);
                h4[q] = (short)h;
                l4[q] = (short)f2bf(v[q] - bf2f(h));
            }
            *(short4v*)(ah + j * 4) = h4;
            *(short4v*)(al + j * 4) = l4;
        }
    }
    __syncthreads();
    int lane = tid & 63, wid = tid >> 6;
    int frow = lane & 15, fk8 = (lane >> 4) * 8, fr4 = (lane >> 4) * 4;
    f32x4 acc[2][4];
#pragma unroll
    for (int a = 0; a < 2; ++a)
#pragma unroll
        for (int c = 0; c < 4; ++c) acc[a][c] = {0.f, 0.f, 0.f, 0.f};
    const ushort* wph = Wph + kt * 65536;
    const ushort* wpl = Wpl + kt * 65536;
#pragma unroll
    for (int kk = 0; kk < 8; ++kk) {
        short8 ah0 = *(const short8*)&Ah[(frow)      * 264 + kk * 32 + fk8];
        short8 ah1 = *(const short8*)&Ah[(16 + frow) * 264 + kk * 32 + fk8];
        short8 al0 = *(const short8*)&Al[(frow)      * 264 + kk * 32 + fk8];
        short8 al1 = *(const short8*)&Al[(16 + frow) * 264 + kk * 32 + fk8];
#pragma unroll
        for (int tc = 0; tc < 4; ++tc) {
            int op = wid * 64 + tc * 16 + frow;
            int base = op * 256 + kk * 32 + fk8;
            short8 wh = *(const short8*)&wph[base];
            short8 wl = *(const short8*)&wpl[base];
            acc[0][tc] = __builtin_amdgcn_mfma_f32_16x16x32_bf16(ah0, wh, acc[0][tc], 0, 0, 0);
            acc[0][tc] = __builtin_amdgcn_mfma_f32_16x16x32_bf16(ah0, wl, acc[0][tc], 0, 0, 0);
            acc[0][tc] = __builtin_amdgcn_mfma_f32_16x16x32_bf16(al0, wh, acc[0][tc], 0, 0, 0);
            acc[1][tc] = __builtin_amdgcn_mfma_f32_16x16x32_bf16(ah1, wh, acc[1][tc], 0, 0, 0);
            acc[1][tc] = __builtin_amdgcn_mfma_f32_16x16x32_bf16(ah1, wl, acc[1][tc], 0, 0, 0);
            acc[1][tc] = __builtin_amdgcn_mfma_f32_16x16x32_bf16(al1, wh, acc[1][tc], 0, 0, 0);
        }
    }
#pragma unroll
    for (int tr = 0; tr < 2; ++tr)
#pragma unroll
        for (int tc = 0; tc < 4; ++tc)
#pragma unroll
            for (int r = 0; r < 4; ++r)
                outF[(bm0 + tr * 16 + fr4 + r) * FROW + kt * 256 + wid * 64 + tc * 16 + frow]
                    = acc[tr][tc][r];
}

// ---------------- inverse DFT ----------------
__global__ __launch_bounds__(256) void k_icdft(const float* __restrict__ f,
        const float* __restrict__ IT, float* __restrict__ h, int mode) {
    __shared__ float IT_s[128 * 32];
    __shared__ float f_s[32 * 128];
    int row = blockIdx.x;
    for (int e = threadIdx.x; e < 4096; e += 256) {
        IT_s[e] = IT[e];
        f_s[e]  = f[row * FROW + e];
    }
    __syncthreads();
    int o = threadIdx.x & 127, nh = threadIdx.x >> 7;
    int outbase, ostride;
    if (mode == 0) { outbase = row * HROW + o; ostride = 128; }
    else { outbase = (row >> 7) * 2097152 + (row & 127) * 128 + o; ostride = 16384; }
    for (int nb = 0; nb < 8; ++nb) {
        int n0 = nh * 64 + nb * 8;
        float acc[8];
#pragma unroll
        for (int j = 0; j < 8; ++j) acc[j] = 0.f;
#pragma unroll
        for (int kpb = 0; kpb < 8; ++kpb) {
            int kp0 = kpb * 4;
            float f0 = f_s[kp0 * 128 + o];
            float f1v = f_s[kp0 * 128 + 128 + o];
            float f2v = f_s[kp0 * 128 + 256 + o];
            float f3v = f_s[kp0 * 128 + 384 + o];
#pragma unroll
            for (int j = 0; j < 8; ++j) {
                f32x4 it = *(const f32x4*)&IT_s[(n0 + j) * 32 + kp0];
                acc[j] += f0 * it[0] + f1v * it[1] + f2v * it[2] + f3v * it[3];
            }
        }
        if (mode == 0) {
#pragma unroll
            for (int j = 0; j < 8; ++j) h[outbase + (n0 + j) * ostride] = acc[j];
        } else {
#pragma unroll
            for (int j = 0; j < 8; ++j) h[outbase + (n0 + j) * ostride] += acc[j];
        }
    }
}

// ---------------- fused FFN + LayerNorm (bf16 MFMA), in-place on h ----------------
// 64 rows/block, 4 waves; 4 chunks of 128 hidden cols; hierarchical LN epilogue.
__global__ __launch_bounds__(256) void k_ffn(float* __restrict__ hio,
        const ushort* __restrict__ w0t, const float* __restrict__ b0,
        const ushort* __restrict__ w1t, const float* __restrict__ b1,
        const float* __restrict__ g, const float* __restrict__ bb) {
    __shared__ __align__(16) ushort h1_s[64 * 136];   // 17408 B
    __shared__ float b0_s[512];
    __shared__ float gb_s[256];
    __shared__ float b1_s[128];
    __shared__ float ps_s[64 * 4];
    __shared__ float pq_s[64 * 4];
    __shared__ float mr_s[64 * 2];

    int tid = threadIdx.x;
    int R0 = blockIdx.x * 64;
    for (int e = tid; e < 512; e += 256) b0_s[e] = b0[e];
    if (tid < 128) {
        gb_s[tid] = g[tid];
        gb_s[128 + tid] = bb[tid];
        b1_s[tid] = b1[tid];
    }

    int lane = tid & 63, wid = tid >> 6;
    int frow = lane & 15;        // row (A) / col (B,D) within 16-tile
    int fk8 = (lane >> 4) * 8;   // k offset within 32-slice
    int fr4 = (lane >> 4) * 4;   // D-frag row offset

    // Preload GEMM1 A-frags straight from global fp32 h, convert in-register.
    short8 a1f[4][4];
#pragma unroll
    for (int tr = 0; tr < 4; ++tr)
#pragma unroll
        for (int kk = 0; kk < 4; ++kk) {
            const float* src = &hio[(R0 + tr * 16 + frow) * 128 + kk * 32 + fk8];
            f32x4 v0 = *(const f32x4*)src;
            f32x4 v1 = *(const f32x4*)(src + 4);
            short8 t;
#pragma unroll
            for (int j = 0; j < 4; ++j) {
                t[j]     = (short)f2bf(v0[j]);
                t[4 + j] = (short)f2bf(v1[j]);
            }
            a1f[tr][kk] = t;
        }

    f32x4 acc2[4][2];
#pragma unroll
    for (int a = 0; a < 4; ++a)
#pragma unroll
        for (int c = 0; c < 2; ++c) acc2[a][c] = {0.f, 0.f, 0.f, 0.f};

    for (int hc = 0; hc < 4; ++hc) {
        __syncthreads();   // h1_s free (and, first iter, b0_s staged)
        // GEMM1 chunk: 128 cols; wave covers 32 (2 tc)
#pragma unroll
        for (int tc = 0; tc < 2; ++tc) {
            int lcol = wid * 32 + tc * 16 + frow;
            int hcol = hc * 128 + lcol;
            short8 bfr[4];
#pragma unroll
            for (int kk = 0; kk < 4; ++kk)
                bfr[kk] = *(const short8*)&w0t[hcol * 128 + kk * 32 + fk8];
            f32x4 acc1[4];
#pragma unroll
            for (int a = 0; a < 4; ++a) acc1[a] = {0.f, 0.f, 0.f, 0.f};
#pragma unroll
            for (int kk = 0; kk < 4; ++kk)
#pragma unroll
                for (int tr = 0; tr < 4; ++tr)
                    acc1[tr] = __builtin_amdgcn_mfma_f32_16x16x32_bf16(
                        a1f[tr][kk], bfr[kk], acc1[tr], 0, 0, 0);
            float b0v = b0_s[hcol];
#pragma unroll
            for (int tr = 0; tr < 4; ++tr)
#pragma unroll
                for (int r = 0; r < 4; ++r) {
                    float v = acc1[tr][r] + b0v;
                    h1_s[(tr * 16 + fr4 + r) * 136 + lcol] = f2bf(fmaxf(v, 0.f));
                }
        }
        __syncthreads();
        // GEMM2 partial over this chunk's K=128
#pragma unroll
        for (int kk = 0; kk < 4; ++kk) {
            short8 a2[4];
#pragma unroll
            for (int tr = 0; tr < 4; ++tr)
                a2[tr] = *(const short8*)&h1_s[(tr * 16 + frow) * 136 + kk * 32 + fk8];
#pragma unroll
            for (int tc = 0; tc < 2; ++tc) {
                int ocol = wid * 32 + tc * 16 + frow;
                short8 b2 = *(const short8*)&w1t[ocol * 512 + hc * 128 + kk * 32 + fk8];
#pragma unroll
                for (int tr = 0; tr < 4; ++tr)
                    acc2[tr][tc] = __builtin_amdgcn_mfma_f32_16x16x32_bf16(
                        a2[tr], b2, acc2[tr][tc], 0, 0, 0);
            }
        }
    }
    // Epilogue: +b1, per-wave LN partials (Σ, Σ²) over the wave's 32 cols
    float b1v0 = b1_s[wid * 32 + frow];
    float b1v1 = b1_s[wid * 32 + 16 + frow];
#pragma unroll
    for (int tr = 0; tr < 4; ++tr)
#pragma unroll
        for (int r = 0; r < 4; ++r) {
            float v0 = acc2[tr][0][r] + b1v0;
            float v1 = acc2[tr][1][r] + b1v1;
            acc2[tr][0][r] = v0;
            acc2[tr][1][r] = v1;
            float s = v0 + v1;
            float q = v0 * v0 + v1 * v1;
            s += __shfl_xor(s, 1); q += __shfl_xor(q, 1);
            s += __shfl_xor(s, 2); q += __shfl_xor(q, 2);
            s += __shfl_xor(s, 4); q += __shfl_xor(q, 4);
            s += __shfl_xor(s, 8); q += __shfl_xor(q, 8);
            if (frow == 0) {
                int row_l = tr * 16 + fr4 + r;
                ps_s[row_l * 4 + wid] = s;
                pq_s[row_l * 4 + wid] = q;
            }
        }
    __syncthreads();
    if (tid < 64) {
        float S = ps_s[tid * 4] + ps_s[tid * 4 + 1] + ps_s[tid * 4 + 2] + ps_s[tid * 4 + 3];
        float Q = pq_s[tid * 4] + pq_s[tid * 4 + 1] + pq_s[tid * 4 + 2] + pq_s[tid * 4 + 3];
        float mu = S * (1.0f / 128.0f);
        float var = Q * (1.0f / 128.0f) - mu * mu;
        mr_s[tid * 2] = mu;
        mr_s[tid * 2 + 1] = rsqrtf(fmaxf(var, 0.f) + LN_EPS);
    }
    __syncthreads();
    float g0 = gb_s[wid * 32 + frow],       bb0 = gb_s[128 + wid * 32 + frow];
    float g1 = gb_s[wid * 32 + 16 + frow],  bb1 = gb_s[128 + wid * 32 + 16 + frow];
#pragma unroll
    for (int tr = 0; tr < 4; ++tr)
#pragma unroll
        for (int r = 0; r < 4; ++r) {
            int row_l = tr * 16 + fr4 + r;
            float mu = mr_s[row_l * 2], rs = mr_s[row_l * 2 + 1];
            float* orow = &hio[(R0 + row_l) * 128 + wid * 32];
            orow[frow]      = (acc2[tr][0][r] - mu) * rs * g0 + bb0;
            orow[16 + frow] = (acc2[tr][1][r] - mu) * rs * g1 + bb1;
        }
}

extern "C" void kernel_launch(void* const* d_in, const int* in_sizes, int n_in,
                              void* d_out, int out_size, void* d_ws, size_t ws_size,
                              hipStream_t stream) {
    (void)in_sizes; (void)n_in; (void)out_size; (void)ws_size;
    const float* x   = (const float*)d_in[0];
    const float* w1  = (const float*)d_in[1];
    const float* w2  = (const float*)d_in[2];
    const float* fw0 = (const float*)d_in[3];
    const float* fb0 = (const float*)d_in[4];
    const float* fw1 = (const float*)d_in[5];
    const float* fb1 = (const float*)d_in[6];
    const float* lng = (const float*)d_in[7];
    const float* lnb = (const float*)d_in[8];
    float* out = (float*)d_out;

    char* ws = (char*)d_ws;
    float*  Tc  = (float*)(ws);
    float*  Ts  = (float*)(ws + 8192);
    float*  IT  = (float*)(ws + 16384);
    ushort* Wph = (ushort*)(ws + 32768);                  // 2 MB
    ushort* Wpl = (ushort*)(ws + 32768 + 2097152);        // 2 MB
    ushort* w0t = (ushort*)(ws + 4227072);                // 128 KB
    ushort* w1t = (ushort*)(ws + 4358144);                // 128 KB
    float*  buf0 = (float*)(ws + 4489216);                // F  (33.5 MB)
    float*  buf1 = (float*)(ws + 4489216 + 33554432);     // f  (33.5 MB)

    k_setup<<<1, 256, 0, stream>>>(Tc, Ts, IT);
    k_wcvt <<<256, 256, 0, stream>>>(fw0, fw1, w0t, w1t);

    // y-branch: DFT over n, mix with w1, inverse over n -> h (= d_out)
    k_wpack<<<4096, 256, 0, stream>>>(w1, Wph, Wpl);
    k_fft  <<<2048, 128, 0, stream>>>(x, Tc, Ts, buf0, 0);
    k_mixm <<<1024, 256, 0, stream>>>(buf0, Wph, Wpl, buf1);
    k_icdft<<<2048, 256, 0, stream>>>(buf1, IT, out, 0);

    // x-branch: DFT over m, mix with w2, inverse over m -> h +=
    k_wpack<<<4096, 256, 0, stream>>>(w2, Wph, Wpl);
    k_fft  <<<2048, 128, 0, stream>>>(x, Tc, Ts, buf0, 1);
    k_mixm <<<1024, 256, 0, stream>>>(buf0, Wph, Wpl, buf1);
    k_icdft<<<2048, 256, 0, stream>>>(buf1, IT, out, 1);

    // fused FFN + LayerNorm, in-place on d_out
    k_ffn<<<4096, 256, 0, stream>>>(out, w0t, fb0, w1t, fb1, lng, lnb);
}

// Round 4
// 531.325 us; speedup vs baseline: 1.4715x; 1.0614x over previous
//
#include <hip/hip_runtime.h>

// Geo-FFNO forward: factored Fourier (DFT -> per-mode complex mix -> iDFT, 16 modes)
// + fused FFN (Linear 128->512, ReLU, Linear 512->128, +bias, LayerNorm).
// B=16, M=N=128, D=I=O=128, NM=16, H=512.
//
// R4: k_ffn was HBM-bound at 11% efficiency (scattered 16B gathers + 4B stores).
//  - k_icdft mode1 now writes the branch-sum as bf16 (hbf, 67 MB) -> halves FFN input
//    traffic and keeps it L3-hot (ws_size-guarded, f32 fallback).
//  - k_ffn: coalesced LDS staging of h, coalesced f32x4 epilogue via LDS union,
//    4 blocks/CU (38.9 KB LDS, ~110 VGPR).

#define LN_EPS 1e-5f
#define NMODES 16
#define FROW 4096     // per-row F/f size: 16k * 2 * 128
#define HROW 16384    // per (b,m) h row: 128*128

typedef __attribute__((ext_vector_type(8))) short short8;
typedef __attribute__((ext_vector_type(8))) ushort ushort8;
typedef __attribute__((ext_vector_type(4))) short short4v;
typedef __attribute__((ext_vector_type(4))) float f32x4;

__device__ __forceinline__ ushort f2bf(float f) {
    unsigned u = __float_as_uint(f);
    unsigned r = (u + 0x7FFFu + ((u >> 16) & 1u)) >> 16;   // RNE
    return (ushort)r;
}
__device__ __forceinline__ float bf2f(ushort h) {
    return __uint_as_float(((unsigned)h) << 16);
}

// ---------------- tables ----------------
__global__ void k_setup(float* __restrict__ Tc, float* __restrict__ Ts,
                        float* __restrict__ IT) {
    const float invs = 0.08838834764831845f;  // 1/sqrt(128)
    for (int idx = threadIdx.x; idx < NMODES * 128; idx += blockDim.x) {
        int k = idx >> 7, n = idx & 127;
        int p = (k * n) & 127;                 // periodic reduction
        float th = (float)p * (6.283185307179586f / 128.0f);
        float c = cosf(th), s = sinf(th);
        Tc[idx] = c * invs;                    // forward: (1/sqrtN) cos
        Ts[idx] = -s * invs;                   // forward: -(1/sqrtN) sin
        float ck = (k == 0) ? invs : 2.0f * invs;
        IT[n * 32 + 2 * k]     = ck * c;       // inverse: c_k cos
        IT[n * 32 + 2 * k + 1] = -ck * s;      // inverse: -c_k sin
    }
}

// ---------------- packed complex-mix weights, transposed, bf16 hi/lo ----------------
// Layout: [k][op][ip]; value(ip,op): ip<128: (op<128? re : im); ip>=128: (op<128? -im : re)
__global__ void k_wpack(const float* __restrict__ w, ushort* __restrict__ Wph,
                        ushort* __restrict__ Wpl) {
    int idx = blockIdx.x * 256 + threadIdx.x;  // 16*256*256 = 1,048,576
    int k  = idx >> 16;
    int op = (idx >> 8) & 255;
    int ip = idx & 255;
    int i = ip & 127, o = op & 127;
    const float* base = w + (((i << 7) | o) * NMODES + k) * 2;
    float re = base[0], im = base[1];
    float v = (ip < 128) ? ((op < 128) ? re : im)
                         : ((op < 128) ? -im : re);
    ushort hi = f2bf(v);
    ushort lo = f2bf(v - bf2f(hi));
    Wph[idx] = hi;
    Wpl[idx] = lo;
}

// ---------------- bf16 FFN weights (once) ----------------
// w0t[h][k] = w0[k][h]  (512x128 bf16); w1t[o][h] = w1[h][o]  (128x512 bf16)
__global__ __launch_bounds__(256) void k_wcvt(const float* __restrict__ w0,
        const float* __restrict__ w1, ushort* __restrict__ w0t,
        ushort* __restrict__ w1t) {
    int idx = blockIdx.x * 256 + threadIdx.x;   // 65536
    int h = idx >> 7, k = idx & 127;
    w0t[idx] = f2bf(w0[k * 512 + h]);
    int o = idx >> 9, hh = idx & 511;
    w1t[idx] = f2bf(w1[hh * 128 + o]);
}

// ---------------- truncated forward DFT ----------------
__global__ __launch_bounds__(128) void k_fft(const float* __restrict__ x,
        const float* __restrict__ Tc, const float* __restrict__ Ts,
        float* __restrict__ F, int mode) {
    __shared__ float Tc_s[NMODES * 128];
    __shared__ float Ts_s[NMODES * 128];
    for (int e = threadIdx.x; e < NMODES * 128; e += 128) {
        Tc_s[e] = Tc[e];
        Ts_s[e] = Ts[e];
    }
    __syncthreads();
    int row = blockIdx.x;
    int base, ts;
    if (mode == 0) { base = row * HROW; ts = 128; }
    else { base = (row >> 7) * 2097152 + (row & 127) * 128; ts = 16384; }
    int i = threadIdx.x;
    float re[NMODES], im[NMODES];
#pragma unroll
    for (int k = 0; k < NMODES; ++k) { re[k] = 0.f; im[k] = 0.f; }
    for (int tb = 0; tb < 32; ++tb) {
        int t0 = tb * 4;
        float xv0 = x[base + (t0 + 0) * ts + i];
        float xv1 = x[base + (t0 + 1) * ts + i];
        float xv2 = x[base + (t0 + 2) * ts + i];
        float xv3 = x[base + (t0 + 3) * ts + i];
#pragma unroll
        for (int k = 0; k < NMODES; ++k) {
            f32x4 c4 = *(const f32x4*)&Tc_s[k * 128 + t0];
            f32x4 s4 = *(const f32x4*)&Ts_s[k * 128 + t0];
            re[k] += xv0 * c4[0] + xv1 * c4[1] + xv2 * c4[2] + xv3 * c4[3];
            im[k] += xv0 * s4[0] + xv1 * s4[1] + xv2 * s4[2] + xv3 * s4[3];
        }
    }
    float* outp = F + row * FROW;
#pragma unroll
    for (int k = 0; k < NMODES; ++k) {
        outp[k * 256 + i]       = re[k];
        outp[k * 256 + 128 + i] = im[k];
    }
}

// ---------------- per-mode channel mix, bf16x3 MFMA ----------------
__global__ __launch_bounds__(256) void k_mixm(const float* __restrict__ A,
        const ushort* __restrict__ Wph, const ushort* __restrict__ Wpl,
        float* __restrict__ outF) {
    __shared__ ushort Ah[32 * 264];
    __shared__ ushort Al[32 * 264];
    int tid = threadIdx.x;
    int kt = blockIdx.x & 15;
    int bm0 = (blockIdx.x >> 4) * 32;
    {
        int row = tid >> 3, cg = tid & 7;
        const float* arow = A + (bm0 + row) * FROW + kt * 256 + cg * 32;
        ushort* ah = &Ah[row * 264 + cg * 32];
        ushort* al = &Al[row * 264 + cg * 32];
#pragma unroll
        for (int j = 0; j < 8; ++j) {
            f32x4 v = *(const f32x4*)(arow + j * 4);
            short4v h4, l4;
#pragma unroll
            for (int q = 0; q < 4; ++q) {
                ushort h = f2bf(v[q]);
                h4[q] = (short)h;
                l4[q] = (short)f2bf(v[q] - bf2f(h));
            }
            *(short4v*)(ah + j * 4) = h4;
            *(short4v*)(al + j * 4) = l4;
        }
    }
    __syncthreads();
    int lane = tid & 63, wid = tid >> 6;
    int frow = lane & 15, fk8 = (lane >> 4) * 8, fr4 = (lane >> 4) * 4;
    f32x4 acc[2][4];
#pragma unroll
    for (int a = 0; a < 2; ++a)
#pragma unroll
        for (int c = 0; c < 4; ++c) acc[a][c] = {0.f, 0.f, 0.f, 0.f};
    const ushort* wph = Wph + kt * 65536;
    const ushort* wpl = Wpl + kt * 65536;
#pragma unroll
    for (int kk = 0; kk < 8; ++kk) {
        short8 ah0 = *(const short8*)&Ah[(frow)      * 264 + kk * 32 + fk8];
        short8 ah1 = *(const short8*)&Ah[(16 + frow) * 264 + kk * 32 + fk8];
        short8 al0 = *(const short8*)&Al[(frow)      * 264 + kk * 32 + fk8];
        short8 al1 = *(const short8*)&Al[(16 + frow) * 264 + kk * 32 + fk8];
#pragma unroll
        for (int tc = 0; tc < 4; ++tc) {
            int op = wid * 64 + tc * 16 + frow;
            int base = op * 256 + kk * 32 + fk8;
            short8 wh = *(const short8*)&wph[base];
            short8 wl = *(const short8*)&wpl[base];
            acc[0][tc] = __builtin_amdgcn_mfma_f32_16x16x32_bf16(ah0, wh, acc[0][tc], 0, 0, 0);
            acc[0][tc] = __builtin_amdgcn_mfma_f32_16x16x32_bf16(ah0, wl, acc[0][tc], 0, 0, 0);
            acc[0][tc] = __builtin_amdgcn_mfma_f32_16x16x32_bf16(al0, wh, acc[0][tc], 0, 0, 0);
            acc[1][tc] = __builtin_amdgcn_mfma_f32_16x16x32_bf16(ah1, wh, acc[1][tc], 0, 0, 0);
            acc[1][tc] = __builtin_amdgcn_mfma_f32_16x16x32_bf16(ah1, wl, acc[1][tc], 0, 0, 0);
            acc[1][tc] = __builtin_amdgcn_mfma_f32_16x16x32_bf16(al1, wh, acc[1][tc], 0, 0, 0);
        }
    }
#pragma unroll
    for (int tr = 0; tr < 2; ++tr)
#pragma unroll
        for (int tc = 0; tc < 4; ++tc)
#pragma unroll
            for (int r = 0; r < 4; ++r)
                outF[(bm0 + tr * 16 + fr4 + r) * FROW + kt * 256 + wid * 64 + tc * 16 + frow]
                    = acc[tr][tc][r];
}

// ---------------- inverse DFT ----------------
// mode 0: h32 = hy (write). mode 1: h = hy + hx -> bf16 hbf (use_bf) or h32 += (fallback).
__global__ __launch_bounds__(256) void k_icdft(const float* __restrict__ f,
        const float* __restrict__ IT, float* __restrict__ h,
        ushort* __restrict__ hbf, int mode, int use_bf) {
    __shared__ float IT_s[128 * 32];
    __shared__ float f_s[32 * 128];
    int row = blockIdx.x;
    for (int e = threadIdx.x; e < 4096; e += 256) {
        IT_s[e] = IT[e];
        f_s[e]  = f[row * FROW + e];
    }
    __syncthreads();
    int o = threadIdx.x & 127, nh = threadIdx.x >> 7;
    int outbase, ostride;
    if (mode == 0) { outbase = row * HROW + o; ostride = 128; }
    else { outbase = (row >> 7) * 2097152 + (row & 127) * 128 + o; ostride = 16384; }
    for (int nb = 0; nb < 8; ++nb) {
        int n0 = nh * 64 + nb * 8;
        float acc[8];
#pragma unroll
        for (int j = 0; j < 8; ++j) acc[j] = 0.f;
#pragma unroll
        for (int kpb = 0; kpb < 8; ++kpb) {
            int kp0 = kpb * 4;
            float f0 = f_s[kp0 * 128 + o];
            float f1v = f_s[kp0 * 128 + 128 + o];
            float f2v = f_s[kp0 * 128 + 256 + o];
            float f3v = f_s[kp0 * 128 + 384 + o];
#pragma unroll
            for (int j = 0; j < 8; ++j) {
                f32x4 it = *(const f32x4*)&IT_s[(n0 + j) * 32 + kp0];
                acc[j] += f0 * it[0] + f1v * it[1] + f2v * it[2] + f3v * it[3];
            }
        }
        if (mode == 0) {
#pragma unroll
            for (int j = 0; j < 8; ++j) h[outbase + (n0 + j) * ostride] = acc[j];
        } else if (use_bf) {
#pragma unroll
            for (int j = 0; j < 8; ++j) {
                int ix = outbase + (n0 + j) * ostride;
                hbf[ix] = f2bf(h[ix] + acc[j]);
            }
        } else {
#pragma unroll
            for (int j = 0; j < 8; ++j) h[outbase + (n0 + j) * ostride] += acc[j];
        }
    }
}

// ---------------- fused FFN + LayerNorm (bf16 MFMA) ----------------
// 64 rows/block, 4 waves. Coalesced LDS staging of h (bf16), weights from L2,
// h1 chunked in LDS, shfl-LN, coalesced f32x4 epilogue via LDS union.
__global__ __launch_bounds__(256) void k_ffn(const ushort* __restrict__ hbf,
        const float* __restrict__ h32, float* __restrict__ out,
        const ushort* __restrict__ w0t, const float* __restrict__ b0,
        const ushort* __restrict__ w1t, const float* __restrict__ b1,
        const float* __restrict__ g, const float* __restrict__ bb, int use_bf) {
    __shared__ __align__(16) char smem[34816];
    ushort* h_s  = (ushort*)smem;                    // [64][136] bf16 (stage + A-frags)
    ushort* h1_s = (ushort*)(smem + 17408);          // [64][136] bf16 (hidden chunk)
    float*  h2f  = (float*)smem;                     // [64][132] f32 (reuse after GEMMs)
    float*  ps_s = (float*)(smem + 33792);           // [256] LN partial sums
    __shared__ float b0q_s[512];                     // b0; reused as pq after GEMMs
    __shared__ float gb_s[256];
    __shared__ float b1_s[128];
    __shared__ float mr_s[128];                      // mu [0..63], rstd [64..127]

    int tid = threadIdx.x;
    int R0 = blockIdx.x * 64;
    {   // coalesced stage: 4 threads per row, 32 cols each
        int srow = tid >> 2, scol = (tid & 3) * 32;
        if (use_bf) {
            const ushort* src = hbf + (R0 + srow) * 128 + scol;
#pragma unroll
            for (int j = 0; j < 4; ++j)
                *(ushort8*)&h_s[srow * 136 + scol + j * 8] = *(const ushort8*)(src + j * 8);
        } else {
            const float* src = h32 + (R0 + srow) * 128 + scol;
#pragma unroll
            for (int j = 0; j < 4; ++j) {
                f32x4 v0 = *(const f32x4*)(src + j * 8);
                f32x4 v1 = *(const f32x4*)(src + j * 8 + 4);
                ushort8 t;
#pragma unroll
                for (int q = 0; q < 4; ++q) { t[q] = f2bf(v0[q]); t[4 + q] = f2bf(v1[q]); }
                *(ushort8*)&h_s[srow * 136 + scol + j * 8] = t;
            }
        }
    }
    for (int e = tid; e < 512; e += 256) b0q_s[e] = b0[e];
    if (tid < 128) { gb_s[tid] = g[tid]; gb_s[128 + tid] = bb[tid]; b1_s[tid] = b1[tid]; }
    __syncthreads();

    int lane = tid & 63, wid = tid >> 6;
    int frow = lane & 15, fk8 = (lane >> 4) * 8, fr4 = (lane >> 4) * 4;

    f32x4 acc2[4][2];
#pragma unroll
    for (int a = 0; a < 4; ++a)
#pragma unroll
        for (int c = 0; c < 2; ++c) acc2[a][c] = {0.f, 0.f, 0.f, 0.f};

    for (int hc = 0; hc < 4; ++hc) {
        // GEMM1: chunk cols 128; wave covers 32 (tc=2)
#pragma unroll
        for (int tc = 0; tc < 2; ++tc) {
            int lcol = wid * 32 + tc * 16 + frow;
            int hcol = hc * 128 + lcol;
            short8 bfr[4];
#pragma unroll
            for (int kk = 0; kk < 4; ++kk)
                bfr[kk] = *(const short8*)&w0t[hcol * 128 + kk * 32 + fk8];
            f32x4 acc1[4];
#pragma unroll
            for (int a = 0; a < 4; ++a) acc1[a] = {0.f, 0.f, 0.f, 0.f};
#pragma unroll
            for (int kk = 0; kk < 4; ++kk)
#pragma unroll
                for (int tr = 0; tr < 4; ++tr) {
                    short8 av = *(const short8*)&h_s[(tr * 16 + frow) * 136 + kk * 32 + fk8];
                    acc1[tr] = __builtin_amdgcn_mfma_f32_16x16x32_bf16(
                        av, bfr[kk], acc1[tr], 0, 0, 0);
                }
            float b0v = b0q_s[hcol];
#pragma unroll
            for (int tr = 0; tr < 4; ++tr)
#pragma unroll
                for (int r = 0; r < 4; ++r) {
                    float v = acc1[tr][r] + b0v;
                    h1_s[(tr * 16 + fr4 + r) * 136 + lcol] = f2bf(fmaxf(v, 0.f));
                }
        }
        __syncthreads();
        // GEMM2 over this chunk's K=128
#pragma unroll
        for (int tc = 0; tc < 2; ++tc) {
            int ocol = wid * 32 + tc * 16 + frow;
            short8 b2f[4];
#pragma unroll
            for (int kk = 0; kk < 4; ++kk)
                b2f[kk] = *(const short8*)&w1t[ocol * 512 + hc * 128 + kk * 32 + fk8];
#pragma unroll
            for (int kk = 0; kk < 4; ++kk)
#pragma unroll
                for (int tr = 0; tr < 4; ++tr) {
                    short8 a2 = *(const short8*)&h1_s[(tr * 16 + frow) * 136 + kk * 32 + fk8];
                    acc2[tr][tc] = __builtin_amdgcn_mfma_f32_16x16x32_bf16(
                        a2, b2f[kk], acc2[tr][tc], 0, 0, 0);
                }
        }
        __syncthreads();   // h1_s consumed; next chunk may overwrite
    }

    // Epilogue: +b1, shfl LN partials
    float* pq_s = b0q_s;   // b0 dead after last GEMM1
    float b1v0 = b1_s[wid * 32 + frow];
    float b1v1 = b1_s[wid * 32 + 16 + frow];
#pragma unroll
    for (int tr = 0; tr < 4; ++tr)
#pragma unroll
        for (int r = 0; r < 4; ++r) {
            float v0 = acc2[tr][0][r] + b1v0;
            float v1 = acc2[tr][1][r] + b1v1;
            acc2[tr][0][r] = v0;
            acc2[tr][1][r] = v1;
            float s = v0 + v1;
            float q = v0 * v0 + v1 * v1;
            s += __shfl_xor(s, 1); q += __shfl_xor(q, 1);
            s += __shfl_xor(s, 2); q += __shfl_xor(q, 2);
            s += __shfl_xor(s, 4); q += __shfl_xor(q, 4);
            s += __shfl_xor(s, 8); q += __shfl_xor(q, 8);
            if (frow == 0) {
                int row_l = tr * 16 + fr4 + r;
                ps_s[row_l * 4 + wid] = s;
                pq_s[row_l * 4 + wid] = q;
            }
        }
    __syncthreads();
    if (tid < 64) {
        float S = ps_s[tid * 4] + ps_s[tid * 4 + 1] + ps_s[tid * 4 + 2] + ps_s[tid * 4 + 3];
        float Q = pq_s[tid * 4] + pq_s[tid * 4 + 1] + pq_s[tid * 4 + 2] + pq_s[tid * 4 + 3];
        float mu = S * (1.0f / 128.0f);
        float var = Q * (1.0f / 128.0f) - mu * mu;
        mr_s[tid] = mu;
        mr_s[64 + tid] = rsqrtf(fmaxf(var, 0.f) + LN_EPS);
    }
    __syncthreads();
    // normalized values -> h2f (union over h_s/h1_s, both dead)
    float g0 = gb_s[wid * 32 + frow],      c0 = gb_s[128 + wid * 32 + frow];
    float g1 = gb_s[wid * 32 + 16 + frow], c1 = gb_s[128 + wid * 32 + 16 + frow];
#pragma unroll
    for (int tr = 0; tr < 4; ++tr)
#pragma unroll
        for (int r = 0; r < 4; ++r) {
            int row_l = tr * 16 + fr4 + r;
            float mu = mr_s[row_l], rs = mr_s[64 + row_l];
            h2f[row_l * 132 + wid * 32 + frow]      = (acc2[tr][0][r] - mu) * rs * g0 + c0;
            h2f[row_l * 132 + wid * 32 + 16 + frow] = (acc2[tr][1][r] - mu) * rs * g1 + c1;
        }
    __syncthreads();
    {   // coalesced f32x4 output
        int srow = tid >> 2, scol = (tid & 3) * 32;
        float* dst = out + (R0 + srow) * 128 + scol;
#pragma unroll
        for (int j = 0; j < 8; ++j)
            *(f32x4*)(dst + j * 4) = *(const f32x4*)&h2f[srow * 132 + scol + j * 4];
    }
}

extern "C" void kernel_launch(void* const* d_in, const int* in_sizes, int n_in,
                              void* d_out, int out_size, void* d_ws, size_t ws_size,
                              hipStream_t stream) {
    (void)in_sizes; (void)n_in; (void)out_size;
    const float* x   = (const float*)d_in[0];
    const float* w1  = (const float*)d_in[1];
    const float* w2  = (const float*)d_in[2];
    const float* fw0 = (const float*)d_in[3];
    const float* fb0 = (const float*)d_in[4];
    const float* fw1 = (const float*)d_in[5];
    const float* fb1 = (const float*)d_in[6];
    const float* lng = (const float*)d_in[7];
    const float* lnb = (const float*)d_in[8];
    float* out = (float*)d_out;

    char* ws = (char*)d_ws;
    float*  Tc  = (float*)(ws);
    float*  Ts  = (float*)(ws + 8192);
    float*  IT  = (float*)(ws + 16384);
    ushort* Wph = (ushort*)(ws + 32768);                  // 2 MB
    ushort* Wpl = (ushort*)(ws + 32768 + 2097152);        // 2 MB
    ushort* w0t = (ushort*)(ws + 4227072);                // 128 KB
    ushort* w1t = (ushort*)(ws + 4358144);                // 128 KB
    float*  buf0 = (float*)(ws + 4489216);                // F  (33.5 MB)
    float*  buf1 = (float*)(ws + 4489216 + 33554432);     // f  (33.5 MB)
    ushort* hbf  = (ushort*)(ws + 71598080);              // h bf16 (67 MB)
    const size_t need = 71598080ull + 67108864ull;
    int use_bf = (ws_size >= need) ? 1 : 0;

    k_setup<<<1, 256, 0, stream>>>(Tc, Ts, IT);
    k_wcvt <<<256, 256, 0, stream>>>(fw0, fw1, w0t, w1t);

    // y-branch: DFT over n, mix with w1, inverse over n -> hy (= d_out, f32)
    k_wpack<<<4096, 256, 0, stream>>>(w1, Wph, Wpl);
    k_fft  <<<2048, 128, 0, stream>>>(x, Tc, Ts, buf0, 0);
    k_mixm <<<1024, 256, 0, stream>>>(buf0, Wph, Wpl, buf1);
    k_icdft<<<2048, 256, 0, stream>>>(buf1, IT, out, hbf, 0, use_bf);

    // x-branch: DFT over m, mix with w2, inverse over m -> h = hy + hx (bf16 hbf)
    k_wpack<<<4096, 256, 0, stream>>>(w2, Wph, Wpl);
    k_fft  <<<2048, 128, 0, stream>>>(x, Tc, Ts, buf0, 1);
    k_mixm <<<1024, 256, 0, stream>>>(buf0, Wph, Wpl, buf1);
    k_icdft<<<2048, 256, 0, stream>>>(buf1, IT, out, hbf, 1, use_bf);

    // fused FFN + LayerNorm -> d_out
    k_ffn<<<4096, 256, 0, stream>>>(hbf, out, out, w0t, fb0, w1t, fb1, lng, lnb, use_bf);
}

// Round 5
// 522.537 us; speedup vs baseline: 1.4963x; 1.0168x over previous
//
#include <hip/hip_runtime.h>

// Geo-FFNO forward: factored Fourier (DFT -> per-mode complex mix -> iDFT, 16 modes)
// + fused FFN (Linear 128->512, ReLU, Linear 512->128, +bias, LayerNorm).
// B=16, M=N=128, D=I=O=128, NM=16, H=512.
//
// R5: k_ffn -> 1-wave blocks (zero barriers, in-register LN, weights from L2,
//     wave-private LDS h1 roundtrip). Both iDFT branches write contiguous bf16
//     in their own layout (hy[b,m,n,o], hx[b,n,m,o]); k_ffn stages the transpose
//     as coalesced 256B reads and sums in f32. k_mixm runs in-place (buf1 dropped).

#define LN_EPS 1e-5f
#define NMODES 16
#define FROW 4096     // per-row F/f size: 16k * 2 * 128
#define HROW 16384    // per (b,m) h row: 128*128

typedef __attribute__((ext_vector_type(8))) short short8;
typedef __attribute__((ext_vector_type(8))) ushort ushort8;
typedef __attribute__((ext_vector_type(4))) short short4v;
typedef __attribute__((ext_vector_type(4))) float f32x4;

__device__ __forceinline__ ushort f2bf(float f) {
    unsigned u = __float_as_uint(f);
    unsigned r = (u + 0x7FFFu + ((u >> 16) & 1u)) >> 16;   // RNE
    return (ushort)r;
}
__device__ __forceinline__ float bf2f(ushort h) {
    return __uint_as_float(((unsigned)h) << 16);
}

// ---------------- tables ----------------
__global__ void k_setup(float* __restrict__ Tc, float* __restrict__ Ts,
                        float* __restrict__ IT) {
    const float invs = 0.08838834764831845f;  // 1/sqrt(128)
    for (int idx = threadIdx.x; idx < NMODES * 128; idx += blockDim.x) {
        int k = idx >> 7, n = idx & 127;
        int p = (k * n) & 127;                 // periodic reduction
        float th = (float)p * (6.283185307179586f / 128.0f);
        float c = cosf(th), s = sinf(th);
        Tc[idx] = c * invs;                    // forward: (1/sqrtN) cos
        Ts[idx] = -s * invs;                   // forward: -(1/sqrtN) sin
        float ck = (k == 0) ? invs : 2.0f * invs;
        IT[n * 32 + 2 * k]     = ck * c;       // inverse: c_k cos
        IT[n * 32 + 2 * k + 1] = -ck * s;      // inverse: -c_k sin
    }
}

// ---------------- packed complex-mix weights, transposed, bf16 hi/lo ----------------
// Layout: [k][op][ip]; value(ip,op): ip<128: (op<128? re : im); ip>=128: (op<128? -im : re)
__global__ void k_wpack(const float* __restrict__ w, ushort* __restrict__ Wph,
                        ushort* __restrict__ Wpl) {
    int idx = blockIdx.x * 256 + threadIdx.x;  // 16*256*256 = 1,048,576
    int k  = idx >> 16;
    int op = (idx >> 8) & 255;
    int ip = idx & 255;
    int i = ip & 127, o = op & 127;
    const float* base = w + (((i << 7) | o) * NMODES + k) * 2;
    float re = base[0], im = base[1];
    float v = (ip < 128) ? ((op < 128) ? re : im)
                         : ((op < 128) ? -im : re);
    ushort hi = f2bf(v);
    ushort lo = f2bf(v - bf2f(hi));
    Wph[idx] = hi;
    Wpl[idx] = lo;
}

// ---------------- bf16 FFN weights (once) ----------------
// w0t[h][k] = w0[k][h]  (512x128 bf16); w1t[o][h] = w1[h][o]  (128x512 bf16)
__global__ __launch_bounds__(256) void k_wcvt(const float* __restrict__ w0,
        const float* __restrict__ w1, ushort* __restrict__ w0t,
        ushort* __restrict__ w1t) {
    int idx = blockIdx.x * 256 + threadIdx.x;   // 65536
    int h = idx >> 7, k = idx & 127;
    w0t[idx] = f2bf(w0[k * 512 + h]);
    int o = idx >> 9, hh = idx & 511;
    w1t[idx] = f2bf(w1[hh * 128 + o]);
}

// ---------------- truncated forward DFT ----------------
__global__ __launch_bounds__(128) void k_fft(const float* __restrict__ x,
        const float* __restrict__ Tc, const float* __restrict__ Ts,
        float* __restrict__ F, int mode) {
    __shared__ float Tc_s[NMODES * 128];
    __shared__ float Ts_s[NMODES * 128];
    for (int e = threadIdx.x; e < NMODES * 128; e += 128) {
        Tc_s[e] = Tc[e];
        Ts_s[e] = Ts[e];
    }
    __syncthreads();
    int row = blockIdx.x;
    int base, ts;
    if (mode == 0) { base = row * HROW; ts = 128; }
    else { base = (row >> 7) * 2097152 + (row & 127) * 128; ts = 16384; }
    int i = threadIdx.x;
    float re[NMODES], im[NMODES];
#pragma unroll
    for (int k = 0; k < NMODES; ++k) { re[k] = 0.f; im[k] = 0.f; }
    for (int tb = 0; tb < 32; ++tb) {
        int t0 = tb * 4;
        float xv0 = x[base + (t0 + 0) * ts + i];
        float xv1 = x[base + (t0 + 1) * ts + i];
        float xv2 = x[base + (t0 + 2) * ts + i];
        float xv3 = x[base + (t0 + 3) * ts + i];
#pragma unroll
        for (int k = 0; k < NMODES; ++k) {
            f32x4 c4 = *(const f32x4*)&Tc_s[k * 128 + t0];
            f32x4 s4 = *(const f32x4*)&Ts_s[k * 128 + t0];
            re[k] += xv0 * c4[0] + xv1 * c4[1] + xv2 * c4[2] + xv3 * c4[3];
            im[k] += xv0 * s4[0] + xv1 * s4[1] + xv2 * s4[2] + xv3 * s4[3];
        }
    }
    float* outp = F + row * FROW;
#pragma unroll
    for (int k = 0; k < NMODES; ++k) {
        outp[k * 256 + i]       = re[k];
        outp[k * 256 + 128 + i] = im[k];
    }
}

// ---------------- per-mode channel mix, bf16x3 MFMA (in-place safe) ----------------
__global__ __launch_bounds__(256) void k_mixm(const float* __restrict__ A,
        const ushort* __restrict__ Wph, const ushort* __restrict__ Wpl,
        float* __restrict__ outF) {
    __shared__ ushort Ah[32 * 264];
    __shared__ ushort Al[32 * 264];
    int tid = threadIdx.x;
    int kt = blockIdx.x & 15;
    int bm0 = (blockIdx.x >> 4) * 32;
    {
        int row = tid >> 3, cg = tid & 7;
        const float* arow = A + (bm0 + row) * FROW + kt * 256 + cg * 32;
        ushort* ah = &Ah[row * 264 + cg * 32];
        ushort* al = &Al[row * 264 + cg * 32];
#pragma unroll
        for (int j = 0; j < 8; ++j) {
            f32x4 v = *(const f32x4*)(arow + j * 4);
            short4v h4, l4;
#pragma unroll
            for (int q = 0; q < 4; ++q) {
                ushort h = f2bf(v[q]);
                h4[q] = (short)h;
                l4[q] = (short)f2bf(v[q] - bf2f(h));
            }
            *(short4v*)(ah + j * 4) = h4;
            *(short4v*)(al + j * 4) = l4;
        }
    }
    __syncthreads();
    int lane = tid & 63, wid = tid >> 6;
    int frow = lane & 15, fk8 = (lane >> 4) * 8, fr4 = (lane >> 4) * 4;
    f32x4 acc[2][4];
#pragma unroll
    for (int a = 0; a < 2; ++a)
#pragma unroll
        for (int c = 0; c < 4; ++c) acc[a][c] = {0.f, 0.f, 0.f, 0.f};
    const ushort* wph = Wph + kt * 65536;
    const ushort* wpl = Wpl + kt * 65536;
#pragma unroll
    for (int kk = 0; kk < 8; ++kk) {
        short8 ah0 = *(const short8*)&Ah[(frow)      * 264 + kk * 32 + fk8];
        short8 ah1 = *(const short8*)&Ah[(16 + frow) * 264 + kk * 32 + fk8];
        short8 al0 = *(const short8*)&Al[(frow)      * 264 + kk * 32 + fk8];
        short8 al1 = *(const short8*)&Al[(16 + frow) * 264 + kk * 32 + fk8];
#pragma unroll
        for (int tc = 0; tc < 4; ++tc) {
            int op = wid * 64 + tc * 16 + frow;
            int base = op * 256 + kk * 32 + fk8;
            short8 wh = *(const short8*)&wph[base];
            short8 wl = *(const short8*)&wpl[base];
            acc[0][tc] = __builtin_amdgcn_mfma_f32_16x16x32_bf16(ah0, wh, acc[0][tc], 0, 0, 0);
            acc[0][tc] = __builtin_amdgcn_mfma_f32_16x16x32_bf16(ah0, wl, acc[0][tc], 0, 0, 0);
            acc[0][tc] = __builtin_amdgcn_mfma_f32_16x16x32_bf16(al0, wh, acc[0][tc], 0, 0, 0);
            acc[1][tc] = __builtin_amdgcn_mfma_f32_16x16x32_bf16(ah1, wh, acc[1][tc], 0, 0, 0);
            acc[1][tc] = __builtin_amdgcn_mfma_f32_16x16x32_bf16(ah1, wl, acc[1][tc], 0, 0, 0);
            acc[1][tc] = __builtin_amdgcn_mfma_f32_16x16x32_bf16(al1, wh, acc[1][tc], 0, 0, 0);
        }
    }
#pragma unroll
    for (int tr = 0; tr < 2; ++tr)
#pragma unroll
        for (int tc = 0; tc < 4; ++tc)
#pragma unroll
            for (int r = 0; r < 4; ++r)
                outF[(bm0 + tr * 16 + fr4 + r) * FROW + kt * 256 + wid * 64 + tc * 16 + frow]
                    = acc[tr][tc][r];
}

// ---------------- inverse DFT ----------------
// mode 0: contiguous bf16 write in the branch's own layout: obf[row*16384 + t*128 + o]
// mode 1 (fallback y): f32 h32[row*HROW + ...] = acc
// mode 2 (fallback x): RMW scatter: hbfs[ix] = bf16(h32[ix] + acc)
__global__ __launch_bounds__(256) void k_icdft(const float* __restrict__ f,
        const float* __restrict__ IT, ushort* __restrict__ obf,
        float* __restrict__ h32, ushort* __restrict__ hbfs, int mode) {
    __shared__ float IT_s[128 * 32];
    __shared__ float f_s[32 * 128];
    int row = blockIdx.x;
    for (int e = threadIdx.x; e < 4096; e += 256) {
        IT_s[e] = IT[e];
        f_s[e]  = f[row * FROW + e];
    }
    __syncthreads();
    int o = threadIdx.x & 127, nh = threadIdx.x >> 7;
    for (int nb = 0; nb < 8; ++nb) {
        int n0 = nh * 64 + nb * 8;
        float acc[8];
#pragma unroll
        for (int j = 0; j < 8; ++j) acc[j] = 0.f;
#pragma unroll
        for (int kpb = 0; kpb < 8; ++kpb) {
            int kp0 = kpb * 4;
            float f0 = f_s[kp0 * 128 + o];
            float f1v = f_s[kp0 * 128 + 128 + o];
            float f2v = f_s[kp0 * 128 + 256 + o];
            float f3v = f_s[kp0 * 128 + 384 + o];
#pragma unroll
            for (int j = 0; j < 8; ++j) {
                f32x4 it = *(const f32x4*)&IT_s[(n0 + j) * 32 + kp0];
                acc[j] += f0 * it[0] + f1v * it[1] + f2v * it[2] + f3v * it[3];
            }
        }
        if (mode == 0) {
#pragma unroll
            for (int j = 0; j < 8; ++j)
                obf[row * HROW + (n0 + j) * 128 + o] = f2bf(acc[j]);
        } else if (mode == 1) {
#pragma unroll
            for (int j = 0; j < 8; ++j)
                h32[row * HROW + (n0 + j) * 128 + o] = acc[j];
        } else {
#pragma unroll
            for (int j = 0; j < 8; ++j) {
                int ix = (row >> 7) * 2097152 + (row & 127) * 128 + o + (n0 + j) * 16384;
                hbfs[ix] = f2bf(h32[ix] + acc[j]);
            }
        }
    }
}

// ---------------- fused FFN + LayerNorm: 1-wave blocks, zero barriers ----------------
// Each 64-lane wave owns 64 rows. 16 chunks of 32 hidden: GEMM1 -> wave-private
// LDS h1 -> GEMM2 K-step. LN fully in-register via shfl_xor; direct stores.
__global__ __launch_bounds__(64, 2) void k_ffn(const ushort* __restrict__ hy,
        const ushort* __restrict__ hx, const ushort* __restrict__ hbfs,
        float* __restrict__ out,
        const ushort* __restrict__ w0t, const float* __restrict__ b0,
        const ushort* __restrict__ w1t, const float* __restrict__ b1,
        const float* __restrict__ g, const float* __restrict__ bb, int two) {
    __shared__ __align__(16) ushort h_s[64 * 136];   // 17408 B
    __shared__ __align__(16) ushort h1_s[64 * 40];   //  5120 B
    int lane = threadIdx.x;
    int R0 = blockIdx.x * 64;

    if (two) {
        int b = R0 >> 14, m = (R0 >> 7) & 127, n0 = R0 & 127;
        const ushort* hyp = hy + (size_t)R0 * 128;
        const ushort* hxp = hx + (size_t)b * 2097152 + (size_t)n0 * 16384 + m * 128;
        for (int e = lane; e < 1024; e += 64) {
            int rl = e >> 4, c8 = (e & 15) * 8;
            ushort8 a = *(const ushort8*)&hyp[rl * 128 + c8];
            ushort8 c = *(const ushort8*)&hxp[rl * 16384 + c8];
            ushort8 t;
#pragma unroll
            for (int j = 0; j < 8; ++j) t[j] = f2bf(bf2f(a[j]) + bf2f(c[j]));
            *(ushort8*)&h_s[rl * 136 + c8] = t;
        }
    } else {
        for (int e = lane; e < 1024; e += 64) {
            int rl = e >> 4, c8 = (e & 15) * 8;
            *(ushort8*)&h_s[rl * 136 + c8] =
                *(const ushort8*)&hbfs[(size_t)(R0 + rl) * 128 + c8];
        }
    }
    __syncthreads();   // single wave: cheap

    int frow = lane & 15, qg = lane >> 4;
    int fk8 = qg * 8, fr4 = qg * 4;

    f32x4 acc2[4][8];
#pragma unroll
    for (int a = 0; a < 4; ++a)
#pragma unroll
        for (int c = 0; c < 8; ++c) acc2[a][c] = {0.f, 0.f, 0.f, 0.f};

    for (int ch = 0; ch < 16; ++ch) {
        // ---- GEMM1: 64 rows x 32 hidden, K=128 ----
        short8 bfr[2][4];
#pragma unroll
        for (int tc2 = 0; tc2 < 2; ++tc2)
#pragma unroll
            for (int kk = 0; kk < 4; ++kk)
                bfr[tc2][kk] = *(const short8*)&w0t[(ch * 32 + tc2 * 16 + frow) * 128 + kk * 32 + fk8];
        f32x4 acc1[4][2];
#pragma unroll
        for (int a = 0; a < 4; ++a)
#pragma unroll
            for (int c = 0; c < 2; ++c) acc1[a][c] = {0.f, 0.f, 0.f, 0.f};
#pragma unroll
        for (int kk = 0; kk < 4; ++kk)
#pragma unroll
            for (int tr = 0; tr < 4; ++tr) {
                short8 av = *(const short8*)&h_s[(tr * 16 + frow) * 136 + kk * 32 + fk8];
#pragma unroll
                for (int tc2 = 0; tc2 < 2; ++tc2)
                    acc1[tr][tc2] = __builtin_amdgcn_mfma_f32_16x16x32_bf16(
                        av, bfr[tc2][kk], acc1[tr][tc2], 0, 0, 0);
            }
        // bias + relu -> wave-private h1 (no barrier: same wave)
#pragma unroll
        for (int tc2 = 0; tc2 < 2; ++tc2) {
            float b0v = b0[ch * 32 + tc2 * 16 + frow];
#pragma unroll
            for (int tr = 0; tr < 4; ++tr)
#pragma unroll
                for (int r = 0; r < 4; ++r)
                    h1_s[(tr * 16 + fr4 + r) * 40 + tc2 * 16 + frow] =
                        f2bf(fmaxf(acc1[tr][tc2][r] + b0v, 0.f));
        }
        // ---- GEMM2 K-step: 64 rows x 128 out, K=32 ----
        short8 b2[8];
#pragma unroll
        for (int tc = 0; tc < 8; ++tc)
            b2[tc] = *(const short8*)&w1t[(tc * 16 + frow) * 512 + ch * 32 + fk8];
#pragma unroll
        for (int tr = 0; tr < 4; ++tr) {
            short8 a2 = *(const short8*)&h1_s[(tr * 16 + frow) * 40 + fk8];
#pragma unroll
            for (int tc = 0; tc < 8; ++tc)
                acc2[tr][tc] = __builtin_amdgcn_mfma_f32_16x16x32_bf16(
                    a2, b2[tc], acc2[tr][tc], 0, 0, 0);
        }
    }

    // ---- epilogue: +b1, in-register LN, direct stores ----
    float b1v[8], gv[8], bv[8];
#pragma unroll
    for (int tc = 0; tc < 8; ++tc) {
        int o = tc * 16 + frow;
        b1v[tc] = b1[o]; gv[tc] = g[o]; bv[tc] = bb[o];
    }
#pragma unroll
    for (int tr = 0; tr < 4; ++tr)
#pragma unroll
        for (int r = 0; r < 4; ++r) {
            float s = 0.f, qq = 0.f;
#pragma unroll
            for (int tc = 0; tc < 8; ++tc) {
                float v = acc2[tr][tc][r] + b1v[tc];
                acc2[tr][tc][r] = v;
                s += v; qq += v * v;
            }
            s += __shfl_xor(s, 1); qq += __shfl_xor(qq, 1);
            s += __shfl_xor(s, 2); qq += __shfl_xor(qq, 2);
            s += __shfl_xor(s, 4); qq += __shfl_xor(qq, 4);
            s += __shfl_xor(s, 8); qq += __shfl_xor(qq, 8);
            float mu = s * (1.0f / 128.0f);
            float var = qq * (1.0f / 128.0f) - mu * mu;
            float rs = rsqrtf(fmaxf(var, 0.f) + LN_EPS);
            float* orow = &out[(size_t)(R0 + tr * 16 + fr4 + r) * 128];
#pragma unroll
            for (int tc = 0; tc < 8; ++tc)
                orow[tc * 16 + frow] = (acc2[tr][tc][r] - mu) * rs * gv[tc] + bv[tc];
        }
}

extern "C" void kernel_launch(void* const* d_in, const int* in_sizes, int n_in,
                              void* d_out, int out_size, void* d_ws, size_t ws_size,
                              hipStream_t stream) {
    (void)in_sizes; (void)n_in; (void)out_size;
    const float* x   = (const float*)d_in[0];
    const float* w1  = (const float*)d_in[1];
    const float* w2  = (const float*)d_in[2];
    const float* fw0 = (const float*)d_in[3];
    const float* fb0 = (const float*)d_in[4];
    const float* fw1 = (const float*)d_in[5];
    const float* fb1 = (const float*)d_in[6];
    const float* lng = (const float*)d_in[7];
    const float* lnb = (const float*)d_in[8];
    float* out = (float*)d_out;

    char* ws = (char*)d_ws;
    float*  Tc  = (float*)(ws);
    float*  Ts  = (float*)(ws + 8192);
    float*  IT  = (float*)(ws + 16384);
    ushort* Wph = (ushort*)(ws + 32768);                  // 2 MB
    ushort* Wpl = (ushort*)(ws + 32768 + 2097152);        // 2 MB
    ushort* w0t = (ushort*)(ws + 4227072);                // 128 KB
    ushort* w1t = (ushort*)(ws + 4358144);                // 128 KB
    float*  buf0 = (float*)(ws + 4489216);                // F/f (33.5 MB, in-place mix)
    ushort* hy   = (ushort*)(ws + 38043648);              // 67 MB
    ushort* hx   = (ushort*)(ws + 105152512);             // 67 MB
    const size_t need_two = 172261376ull;
    int two = (ws_size >= need_two) ? 1 : 0;
    // fallback single-buffer: hbfs at the hy slot (needs 105.2 MB)
    ushort* hbfs = hy;

    k_setup<<<1, 256, 0, stream>>>(Tc, Ts, IT);
    k_wcvt <<<256, 256, 0, stream>>>(fw0, fw1, w0t, w1t);

    // y-branch: DFT over n, mix with w1, inverse over n -> hy[b,m,n,o] bf16
    k_wpack<<<4096, 256, 0, stream>>>(w1, Wph, Wpl);
    k_fft  <<<2048, 128, 0, stream>>>(x, Tc, Ts, buf0, 0);
    k_mixm <<<1024, 256, 0, stream>>>(buf0, Wph, Wpl, buf0);
    if (two) k_icdft<<<2048, 256, 0, stream>>>(buf0, IT, hy, out, hbfs, 0);
    else     k_icdft<<<2048, 256, 0, stream>>>(buf0, IT, hy, out, hbfs, 1);

    // x-branch: DFT over m, mix with w2, inverse over m -> hx[b,n,m,o] bf16
    k_wpack<<<4096, 256, 0, stream>>>(w2, Wph, Wpl);
    k_fft  <<<2048, 128, 0, stream>>>(x, Tc, Ts, buf0, 1);
    k_mixm <<<1024, 256, 0, stream>>>(buf0, Wph, Wpl, buf0);
    if (two) k_icdft<<<2048, 256, 0, stream>>>(buf0, IT, hx, out, hbfs, 0);
    else     k_icdft<<<2048, 256, 0, stream>>>(buf0, IT, hx, out, hbfs, 2);

    // fused FFN + LayerNorm -> d_out (1-wave blocks)
    k_ffn<<<4096, 64, 0, stream>>>(hy, hx, hbfs, out, w0t, fb0, w1t, fb1, lng, lnb, two);
}